// Round 3
// baseline (639.286 us; speedup 1.0000x reference)
//
#include <hip/hip_runtime.h>
#include <cstdint>
#include <cstddef>

// Problem constants (B=16, T=1024, D=256, K=1024)
namespace {
constexpr int NROW = 16384;   // B*T
constexpr int KC   = 1024;    // codes
constexpr int DIM  = 256;
constexpr int MT   = 128;     // rows per block (argmin GEMM)
constexpr int KTILE= 128;     // codes per k-tile
constexpr int DC   = 16;      // d-chunk staged in LDS
constexpr int PAD  = 132;     // LDS row pad (conflict-free + 16B aligned rows)
constexpr int KSPLIT = 4;     // K partitioned across blocks
constexpr int KPB  = KC / KSPLIT;
constexpr int FCAP = 8192;    // flagged-row capacity (expect ~900)
}

// Monotone float -> uint key (ascending), for packed argmin with index tie-break.
__device__ __forceinline__ unsigned fkey(float s) {
  unsigned u = __float_as_uint(s);
  return ((int)u >= 0) ? (u ^ 0x80000000u) : ~u;
}
__device__ __forceinline__ float unfkey(unsigned u) {
  return __uint_as_float((u & 0x80000000u) ? (u ^ 0x80000000u) : ~u);
}

// numpy pairwise sum of squares of 256 contiguous floats, bit-exact emulation:
// n=256 splits into two 128-blocks; each 128-block uses 8 accumulators with
// mul-round-add-round (NO fma), combined ((r0+r1)+(r2+r3))+((r4+r5)+(r6+r7)).
__device__ __forceinline__ float np_sumsq_256(const float* __restrict__ p) {
  float half[2];
  #pragma unroll
  for (int h = 0; h < 2; h++) {
    const float* q = p + h * 128;
    float r[8];
    #pragma unroll
    for (int j = 0; j < 8; j++) r[j] = __fmul_rn(q[j], q[j]);
    #pragma unroll 1
    for (int i = 8; i < 128; i += 8)
      #pragma unroll
      for (int j = 0; j < 8; j++)
        r[j] = __fadd_rn(r[j], __fmul_rn(q[i + j], q[i + j]));
    half[h] = __fadd_rn(__fadd_rn(__fadd_rn(r[0], r[1]), __fadd_rn(r[2], r[3])),
                        __fadd_rn(__fadd_rn(r[4], r[5]), __fadd_rn(r[6], r[7])));
  }
  return __fadd_rn(half[0], half[1]);
}

// ---------------------------------------------------------------- wnorm ----
// ||w_k||^2 with numpy-pairwise fp32 rounding. One thread per code.
__global__ __launch_bounds__(256)
void wnorm_np_kernel(const float* __restrict__ w, float* __restrict__ wnorm) {
  const int k = blockIdx.x * 256 + threadIdx.x;   // grid = 4 blocks
  wnorm[k] = np_sumsq_256(&w[k * DIM]);
}

// ---------------------------------------------------- distance + top-2 ----
// fp32 GEMM, tracks per-row TOP-2 of s = ||w||^2 - 2 x.w (fine-grained score).
__global__ __launch_bounds__(256, 2)
void dist_argmin_kernel(const float* __restrict__ x, const float* __restrict__ w,
                        const float* __restrict__ wnorm,
                        unsigned long long* __restrict__ pairs) {
  __shared__ union {
    struct { float As[DC][PAD]; float Bs[DC][PAD]; } st;
    unsigned long long red[16][MT][2];
  } sm;

  const int tid = threadIdx.x;
  const int tx  = tid & 15;
  const int ty  = tid >> 4;
  const int rowBase = (blockIdx.x >> 2) * MT;
  const int sp      = blockIdx.x & 3;
  const int kbase   = sp * KPB;

  unsigned long long b0[8], b1[8];
  #pragma unroll
  for (int i = 0; i < 8; i++) { b0[i] = ~0ULL; b1[i] = ~0ULL; }

  #pragma unroll 1
  for (int kt = 0; kt < KPB / KTILE; kt++) {
    const int kstart = kbase + kt * KTILE;

    float acc[8][8];
    #pragma unroll
    for (int i = 0; i < 8; i++)
      #pragma unroll
      for (int j = 0; j < 8; j++) acc[i][j] = 0.0f;

    #pragma unroll 1
    for (int dc = 0; dc < DIM / DC; dc++) {
      __syncthreads();
      #pragma unroll
      for (int i = 0; i < 2; i++) {
        const int l  = tid + i * 256;
        const int r  = l >> 2;
        const int c4 = l & 3;
        const float4 av = *(const float4*)&x[(rowBase + r) * DIM + dc * DC + c4 * 4];
        sm.st.As[c4 * 4 + 0][r] = av.x;
        sm.st.As[c4 * 4 + 1][r] = av.y;
        sm.st.As[c4 * 4 + 2][r] = av.z;
        sm.st.As[c4 * 4 + 3][r] = av.w;
        const float4 bv = *(const float4*)&w[(kstart + r) * DIM + dc * DC + c4 * 4];
        sm.st.Bs[c4 * 4 + 0][r] = bv.x;
        sm.st.Bs[c4 * 4 + 1][r] = bv.y;
        sm.st.Bs[c4 * 4 + 2][r] = bv.z;
        sm.st.Bs[c4 * 4 + 3][r] = bv.w;
      }
      __syncthreads();

      #pragma unroll
      for (int d = 0; d < DC; d++) {
        const float4 a0 = *(const float4*)&sm.st.As[d][tx * 4];
        const float4 a1 = *(const float4*)&sm.st.As[d][tx * 4 + 64];
        const float4 c0 = *(const float4*)&sm.st.Bs[d][ty * 4];
        const float4 c1 = *(const float4*)&sm.st.Bs[d][ty * 4 + 64];
        const float a[8] = {a0.x, a0.y, a0.z, a0.w, a1.x, a1.y, a1.z, a1.w};
        const float b[8] = {c0.x, c0.y, c0.z, c0.w, c1.x, c1.y, c1.z, c1.w};
        #pragma unroll
        for (int i = 0; i < 8; i++)
          #pragma unroll
          for (int j = 0; j < 8; j++)
            acc[i][j] = fmaf(a[i], b[j], acc[i][j]);
      }
    }

    #pragma unroll
    for (int i = 0; i < 8; i++) {
      #pragma unroll
      for (int j = 0; j < 8; j++) {
        const int k = kstart + ty * 4 + (j & 3) + (j >> 2) * 64;
        const float s = fmaf(-2.0f, acc[i][j], wnorm[k]);
        const unsigned long long p =
            ((unsigned long long)fkey(s) << 32) | (unsigned)k;
        if (p < b1[i]) {
          if (p < b0[i]) { b1[i] = b0[i]; b0[i] = p; }
          else           { b1[i] = p; }
        }
      }
    }
  }

  __syncthreads();
  #pragma unroll
  for (int i = 0; i < 8; i++) {
    const int rl = tx * 4 + (i & 3) + (i >> 2) * 64;
    sm.red[ty][rl][0] = b0[i];
    sm.red[ty][rl][1] = b1[i];
  }
  __syncthreads();
  if (tid < MT) {
    unsigned long long B0 = sm.red[0][tid][0];
    unsigned long long B1 = sm.red[0][tid][1];
    #pragma unroll
    for (int t = 1; t < 16; t++) {
      const unsigned long long c0 = sm.red[t][tid][0];
      const unsigned long long c1 = sm.red[t][tid][1];
      if (c0 < B0) { B1 = (B0 < c1) ? B0 : c1; B0 = c0; }
      else         { B1 = (B1 < c0) ? B1 : c0; }
    }
    pairs[(rowBase + tid) * 8 + sp * 2 + 0] = B0;
    pairs[(rowBase + tid) * 8 + sp * 2 + 1] = B1;
  }
}

// ------------------------------------------------- merge splits + flag ----
// Rows whose fine-score top-2 gap < 4e-4 could be reordered by the reference's
// fp32 ulp(256)-grid quantization (bound ~6.1e-5) -> flag for np-emulation.
__global__ __launch_bounds__(256)
void merge_kernel(const unsigned long long* __restrict__ pairs,
                  int* __restrict__ idx, int* __restrict__ flags,
                  int* __restrict__ counter) {
  const int row = blockIdx.x * 256 + threadIdx.x;
  const unsigned long long* p = &pairs[row * 8];
  unsigned long long B0 = p[0], B1 = p[1];
  #pragma unroll
  for (int s = 1; s < KSPLIT; s++) {
    const unsigned long long c0 = p[s * 2], c1 = p[s * 2 + 1];
    if (c0 < B0) { B1 = (B0 < c1) ? B0 : c1; B0 = c0; }
    else         { B1 = (B1 < c0) ? B1 : c0; }
  }
  idx[row] = (int)(B0 & 0xffffffffULL);
  const float s0 = unfkey((unsigned)(B0 >> 32));
  const float s1 = unfkey((unsigned)(B1 >> 32));
  if (s1 - s0 < 4e-4f) {
    const int pos = atomicAdd(counter, 1);
    if (pos < FCAP) flags[pos] = row;
  }
}

// --------------------- np-fp32-emulating recheck of quantization-sensitive rows
// Reproduces: D[k] = fl32( fl32(x2_np + w2_np[k]) - 2*fl32(dot_exact) ),
// argmin with lowest-index tie-break (np.argmin first-occurrence).
__global__ __launch_bounds__(256)
void recheck_np_kernel(const float* __restrict__ x, const float* __restrict__ w,
                       const float* __restrict__ wnorm,
                       const int* __restrict__ flags, const int* __restrict__ counter,
                       int* __restrict__ idx) {
  __shared__ float xs[DIM];
  __shared__ float x2sh;
  __shared__ unsigned long long red[256];
  const int cnt = min(*counter, FCAP);
  for (int f = blockIdx.x; f < cnt; f += gridDim.x) {
    const int row = flags[f];
    __syncthreads();
    xs[threadIdx.x] = x[row * DIM + threadIdx.x];
    __syncthreads();
    if (threadIdx.x == 0) x2sh = np_sumsq_256(xs);
    __syncthreads();
    const double x2d = (double)x2sh;

    unsigned long long best = ~0ULL;
    #pragma unroll 1
    for (int g = 0; g < 4; g++) {
      const int k = threadIdx.x * 4 + g;
      const float* wr = &w[k * DIM];
      double dot = 0.0;
      #pragma unroll 1
      for (int d = 0; d < DIM; d += 4) {
        const float4 wv = *(const float4*)&wr[d];
        dot = fma((double)xs[d],     (double)wv.x, dot);
        dot = fma((double)xs[d + 1], (double)wv.y, dot);
        dot = fma((double)xs[d + 2], (double)wv.z, dot);
        dot = fma((double)xs[d + 3], (double)wv.w, dot);
      }
      const float mmf = (float)dot;                         // fl32(sgemm value)
      const float S1  = (float)(x2d + (double)wnorm[k]);    // fl32(x2 + w2)
      const float D   = (float)((double)S1 - 2.0 * (double)mmf); // fl32(S1 - 2mm)
      const unsigned long long key =
          ((unsigned long long)fkey(D) << 32) | (unsigned)k;
      if (key < best) best = key;
    }
    red[threadIdx.x] = best;
    __syncthreads();
    #pragma unroll
    for (int off = 128; off > 0; off >>= 1) {
      if ((int)threadIdx.x < off) {
        const unsigned long long o = red[threadIdx.x + off];
        if (o < red[threadIdx.x]) red[threadIdx.x] = o;
      }
      __syncthreads();
    }
    if (threadIdx.x == 0) idx[row] = (int)(red[0] & 0xffffffffULL);
    __syncthreads();
  }
}

// ---------------------------------------------------------------- counts ----
__global__ __launch_bounds__(256)
void counts_kernel(const int* __restrict__ idx, float* __restrict__ counts) {
  const int n = blockIdx.x * 256 + threadIdx.x;
  atomicAdd(&counts[idx[n]], 1.0f);
}

// -------------------------------------------------------------------- cs ----
__global__ __launch_bounds__(1024)
void cs_kernel(const float* __restrict__ ema_cs, const float* __restrict__ counts,
               float* __restrict__ out_cs, float* __restrict__ cs_ws) {
  __shared__ float lds[17];
  const int k = threadIdx.x;
  const float c = ema_cs[k] * 0.99f + 0.01f * counts[k];
  float v = c;
  #pragma unroll
  for (int off = 32; off > 0; off >>= 1) v += __shfl_down(v, off);
  if ((k & 63) == 0) lds[k >> 6] = v;
  __syncthreads();
  if (k == 0) {
    float n = 0.0f;
    for (int i = 0; i < 16; i++) n += lds[i];
    lds[16] = n;
  }
  __syncthreads();
  const float n = lds[16];
  const float csv = (c + 1e-5f) / (n + 1024.0f * 1e-5f) * n;
  out_cs[k] = csv;
  cs_ws[k]  = csv;
}

// ------------------------------------- fused quantize + loss + dw scatter ----
__global__ __launch_bounds__(256)
void quant_loss_dw_kernel(const float4* __restrict__ x4,
                          const float4* __restrict__ w4,
                          const int* __restrict__ idx,
                          float4* __restrict__ outq,
                          float* __restrict__ dw,
                          float* __restrict__ partials) {
  __shared__ float lds[4];
  const int g  = blockIdx.x * 256 + threadIdx.x;
  const int n  = g >> 6;
  const int d4 = g & 63;
  const float4 xv = x4[g];
  const int   k  = idx[n];
  const float4 qv = w4[k * 64 + d4];
  float4 r;
  r.x = xv.x + (qv.x - xv.x);
  r.y = xv.y + (qv.y - xv.y);
  r.z = xv.z + (qv.z - xv.z);
  r.w = xv.w + (qv.w - xv.w);
  outq[g] = r;

  float* dst = dw + k * DIM + d4 * 4;
  atomicAdd(dst + 0, xv.x);
  atomicAdd(dst + 1, xv.y);
  atomicAdd(dst + 2, xv.z);
  atomicAdd(dst + 3, xv.w);

  const float dx = xv.x - r.x, dy = xv.y - r.y, dz = xv.z - r.z, dwv = xv.w - r.w;
  float s = dx * dx + dy * dy + dz * dz + dwv * dwv;
  #pragma unroll
  for (int off = 32; off > 0; off >>= 1) s += __shfl_down(s, off);
  if ((threadIdx.x & 63) == 0) lds[threadIdx.x >> 6] = s;
  __syncthreads();
  if (threadIdx.x == 0) partials[blockIdx.x] = lds[0] + lds[1] + lds[2] + lds[3];
}

// ------------------------------------------------- ema_w_new + embed_new ----
__global__ __launch_bounds__(256)
void emb_kernel(const float* __restrict__ ema_w, const float* __restrict__ dw,
                const float* __restrict__ cs,
                float* __restrict__ out_ema_w, float* __restrict__ out_embed) {
  const int g = blockIdx.x * 256 + threadIdx.x;
  const int k = g >> 8;
  const float e = ema_w[g] * 0.99f + 0.01f * dw[g];
  out_ema_w[g] = e;
  out_embed[g] = e / cs[k];
}

// ---------------------------------------------------------- loss finalize ----
__global__ __launch_bounds__(256)
void loss_fin_kernel(const float* __restrict__ partials, float* __restrict__ out_loss) {
  __shared__ float lds[4];
  float s = 0.0f;
  for (int i = threadIdx.x; i < 4096; i += 256) s += partials[i];
  #pragma unroll
  for (int off = 32; off > 0; off >>= 1) s += __shfl_down(s, off);
  if ((threadIdx.x & 63) == 0) lds[threadIdx.x >> 6] = s;
  __syncthreads();
  if (threadIdx.x == 0) {
    const float total = lds[0] + lds[1] + lds[2] + lds[3];
    out_loss[0] = 0.25f * (total / 4194304.0f);
  }
}

// ------------------------------------------------------------------ launch ----
extern "C" void kernel_launch(void* const* d_in, const int* in_sizes, int n_in,
                              void* d_out, int out_size, void* d_ws, size_t ws_size,
                              hipStream_t stream) {
  const float* x       = (const float*)d_in[0];
  const float* embed_w = (const float*)d_in[1];
  const float* ema_cs  = (const float*)d_in[2];
  const float* ema_w   = (const float*)d_in[3];

  float* out        = (float*)d_out;
  float* out_q      = out;                 // 4194304
  float* out_loss   = out + 4194304;       // 1
  float* out_embed  = out + 4194305;       // 262144
  float* out_cs     = out + 4456449;       // 1024
  float* out_ema_w  = out + 4457473;       // 262144

  char* ws = (char*)d_ws;
  unsigned long long* pairs = (unsigned long long*)(ws + 0);   // 1048576 B
  int*   idx      = (int*)  (ws + 1048576);                    // 65536 B
  float* counts   = (float*)(ws + 1114112);                    // 4096 B
  float* dw       = (float*)(ws + 1118208);                    // 1048576 B
  float* cs_ws    = (float*)(ws + 2166784);                    // 4096 B
  float* wnorm    = (float*)(ws + 2170880);                    // 4096 B
  float* partials = (float*)(ws + 2174976);                    // 16384 B
  int*   flags    = (int*)  (ws + 2191360);                    // 32768 B
  int*   counter  = (int*)  (ws + 2224128);                    // 4 B

  hipMemsetAsync(counts, 0, 1052672, stream);   // counts + dw (contiguous)
  hipMemsetAsync(counter, 0, 4, stream);

  wnorm_np_kernel<<<KC / 256, 256, 0, stream>>>(embed_w, wnorm);
  dist_argmin_kernel<<<(NROW / MT) * KSPLIT, 256, 0, stream>>>(x, embed_w, wnorm, pairs);
  merge_kernel<<<NROW / 256, 256, 0, stream>>>(pairs, idx, flags, counter);
  recheck_np_kernel<<<128, 256, 0, stream>>>(x, embed_w, wnorm, flags, counter, idx);
  counts_kernel<<<NROW / 256, 256, 0, stream>>>(idx, counts);
  cs_kernel<<<1, 1024, 0, stream>>>(ema_cs, counts, out_cs, cs_ws);
  quant_loss_dw_kernel<<<NROW * 64 / 256, 256, 0, stream>>>(
      (const float4*)x, (const float4*)embed_w, idx, (float4*)out_q, dw, partials);
  emb_kernel<<<KC * DIM / 256, 256, 0, stream>>>(ema_w, dw, cs_ws, out_ema_w, out_embed);
  loss_fin_kernel<<<1, 256, 0, stream>>>(partials, out_loss);
}

// Round 4
// 381.095 us; speedup vs baseline: 1.6775x; 1.6775x over previous
//
#include <hip/hip_runtime.h>
#include <cstdint>
#include <cstddef>

// Problem constants (B=16, T=1024, D=256, K=1024)
namespace {
constexpr int NROW = 16384;   // B*T
constexpr int KC   = 1024;    // codes
constexpr int DIM  = 256;
constexpr int MT   = 128;     // rows per block (argmin GEMM)
constexpr int KTILE= 128;     // codes per k-tile
constexpr int DC   = 16;      // d-chunk staged in LDS
constexpr int PAD  = 132;     // LDS row pad (conflict-free + 16B aligned rows)
constexpr int KSPLIT = 4;     // K partitioned across blocks
constexpr int KPB  = KC / KSPLIT;
constexpr int FCAP = 8192;    // flagged-row capacity (expect ~900)
constexpr int RPB  = 4;       // flagged rows per recheck block
}

// Monotone float -> uint key (ascending), for packed argmin with index tie-break.
__device__ __forceinline__ unsigned fkey(float s) {
  unsigned u = __float_as_uint(s);
  return ((int)u >= 0) ? (u ^ 0x80000000u) : ~u;
}
__device__ __forceinline__ float unfkey(unsigned u) {
  return __uint_as_float((u & 0x80000000u) ? (u ^ 0x80000000u) : ~u);
}

// numpy pairwise sum of squares of 256 contiguous floats, bit-exact emulation:
// n=256 splits into two 128-blocks; each 128-block uses 8 accumulators with
// mul-round-add-round (NO fma), combined ((r0+r1)+(r2+r3))+((r4+r5)+(r6+r7)).
__device__ __forceinline__ float np_sumsq_256(const float* __restrict__ p) {
  float half[2];
  #pragma unroll
  for (int h = 0; h < 2; h++) {
    const float* q = p + h * 128;
    float r[8];
    #pragma unroll
    for (int j = 0; j < 8; j++) r[j] = __fmul_rn(q[j], q[j]);
    #pragma unroll 1
    for (int i = 8; i < 128; i += 8)
      #pragma unroll
      for (int j = 0; j < 8; j++)
        r[j] = __fadd_rn(r[j], __fmul_rn(q[i + j], q[i + j]));
    half[h] = __fadd_rn(__fadd_rn(__fadd_rn(r[0], r[1]), __fadd_rn(r[2], r[3])),
                        __fadd_rn(__fadd_rn(r[4], r[5]), __fadd_rn(r[6], r[7])));
  }
  return __fadd_rn(half[0], half[1]);
}

// ---------------------------------------------------------------- wnorm ----
__global__ __launch_bounds__(256)
void wnorm_np_kernel(const float* __restrict__ w, float* __restrict__ wnorm) {
  const int k = blockIdx.x * 256 + threadIdx.x;   // grid = 4 blocks
  wnorm[k] = np_sumsq_256(&w[k * DIM]);
}

// ---------------------------------------------------- distance + top-2 ----
// fp32 GEMM, tracks per-row TOP-2 of s = ||w||^2 - 2 x.w (fine-grained score).
__global__ __launch_bounds__(256, 2)
void dist_argmin_kernel(const float* __restrict__ x, const float* __restrict__ w,
                        const float* __restrict__ wnorm,
                        unsigned long long* __restrict__ pairs) {
  __shared__ union {
    struct { float As[DC][PAD]; float Bs[DC][PAD]; } st;
    unsigned long long red[16][MT][2];
  } sm;

  const int tid = threadIdx.x;
  const int tx  = tid & 15;
  const int ty  = tid >> 4;
  const int rowBase = (blockIdx.x >> 2) * MT;
  const int sp      = blockIdx.x & 3;
  const int kbase   = sp * KPB;

  unsigned long long b0[8], b1[8];
  #pragma unroll
  for (int i = 0; i < 8; i++) { b0[i] = ~0ULL; b1[i] = ~0ULL; }

  #pragma unroll 1
  for (int kt = 0; kt < KPB / KTILE; kt++) {
    const int kstart = kbase + kt * KTILE;

    float acc[8][8];
    #pragma unroll
    for (int i = 0; i < 8; i++)
      #pragma unroll
      for (int j = 0; j < 8; j++) acc[i][j] = 0.0f;

    #pragma unroll 1
    for (int dc = 0; dc < DIM / DC; dc++) {
      __syncthreads();
      #pragma unroll
      for (int i = 0; i < 2; i++) {
        const int l  = tid + i * 256;
        const int r  = l >> 2;
        const int c4 = l & 3;
        const float4 av = *(const float4*)&x[(rowBase + r) * DIM + dc * DC + c4 * 4];
        sm.st.As[c4 * 4 + 0][r] = av.x;
        sm.st.As[c4 * 4 + 1][r] = av.y;
        sm.st.As[c4 * 4 + 2][r] = av.z;
        sm.st.As[c4 * 4 + 3][r] = av.w;
        const float4 bv = *(const float4*)&w[(kstart + r) * DIM + dc * DC + c4 * 4];
        sm.st.Bs[c4 * 4 + 0][r] = bv.x;
        sm.st.Bs[c4 * 4 + 1][r] = bv.y;
        sm.st.Bs[c4 * 4 + 2][r] = bv.z;
        sm.st.Bs[c4 * 4 + 3][r] = bv.w;
      }
      __syncthreads();

      #pragma unroll
      for (int d = 0; d < DC; d++) {
        const float4 a0 = *(const float4*)&sm.st.As[d][tx * 4];
        const float4 a1 = *(const float4*)&sm.st.As[d][tx * 4 + 64];
        const float4 c0 = *(const float4*)&sm.st.Bs[d][ty * 4];
        const float4 c1 = *(const float4*)&sm.st.Bs[d][ty * 4 + 64];
        const float a[8] = {a0.x, a0.y, a0.z, a0.w, a1.x, a1.y, a1.z, a1.w};
        const float b[8] = {c0.x, c0.y, c0.z, c0.w, c1.x, c1.y, c1.z, c1.w};
        #pragma unroll
        for (int i = 0; i < 8; i++)
          #pragma unroll
          for (int j = 0; j < 8; j++)
            acc[i][j] = fmaf(a[i], b[j], acc[i][j]);
      }
    }

    #pragma unroll
    for (int i = 0; i < 8; i++) {
      #pragma unroll
      for (int j = 0; j < 8; j++) {
        const int k = kstart + ty * 4 + (j & 3) + (j >> 2) * 64;
        const float s = fmaf(-2.0f, acc[i][j], wnorm[k]);
        const unsigned long long p =
            ((unsigned long long)fkey(s) << 32) | (unsigned)k;
        if (p < b1[i]) {
          if (p < b0[i]) { b1[i] = b0[i]; b0[i] = p; }
          else           { b1[i] = p; }
        }
      }
    }
  }

  __syncthreads();
  #pragma unroll
  for (int i = 0; i < 8; i++) {
    const int rl = tx * 4 + (i & 3) + (i >> 2) * 64;
    sm.red[ty][rl][0] = b0[i];
    sm.red[ty][rl][1] = b1[i];
  }
  __syncthreads();
  if (tid < MT) {
    unsigned long long B0 = sm.red[0][tid][0];
    unsigned long long B1 = sm.red[0][tid][1];
    #pragma unroll
    for (int t = 1; t < 16; t++) {
      const unsigned long long c0 = sm.red[t][tid][0];
      const unsigned long long c1 = sm.red[t][tid][1];
      if (c0 < B0) { B1 = (B0 < c1) ? B0 : c1; B0 = c0; }
      else         { B1 = (B1 < c0) ? B1 : c0; }
    }
    pairs[(rowBase + tid) * 8 + sp * 2 + 0] = B0;
    pairs[(rowBase + tid) * 8 + sp * 2 + 1] = B1;
  }
}

// ------------------------------------------------- merge splits + flag ----
__global__ __launch_bounds__(256)
void merge_kernel(const unsigned long long* __restrict__ pairs,
                  int* __restrict__ idx, int* __restrict__ flags,
                  int* __restrict__ counter) {
  const int row = blockIdx.x * 256 + threadIdx.x;
  const unsigned long long* p = &pairs[row * 8];
  unsigned long long B0 = p[0], B1 = p[1];
  #pragma unroll
  for (int s = 1; s < KSPLIT; s++) {
    const unsigned long long c0 = p[s * 2], c1 = p[s * 2 + 1];
    if (c0 < B0) { B1 = (B0 < c1) ? B0 : c1; B0 = c0; }
    else         { B1 = (B1 < c0) ? B1 : c0; }
  }
  idx[row] = (int)(B0 & 0xffffffffULL);
  const float s0 = unfkey((unsigned)(B0 >> 32));
  const float s1 = unfkey((unsigned)(B1 >> 32));
  if (s1 - s0 < 4e-4f) {
    const int pos = atomicAdd(counter, 1);
    if (pos < FCAP) flags[pos] = row;
  }
}

// --------------------- np-fp32-emulating recheck of quantization-sensitive rows
// One block per RPB flagged rows; 256 threads x 4 codes; fp64 dots with ILP
// across the RPB row-accumulators. Bit-semantics identical to R3's recheck.
__global__ __launch_bounds__(256)
void recheck_np_kernel(const float* __restrict__ x, const float* __restrict__ w,
                       const float* __restrict__ wnorm,
                       const int* __restrict__ flags, const int* __restrict__ counter,
                       int* __restrict__ idx) {
  __shared__ float xs[RPB][DIM];
  __shared__ float x2sh[RPB];
  __shared__ unsigned long long red[RPB][256];

  const int cnt  = min(*counter, FCAP);
  const int base = blockIdx.x * RPB;
  if (base >= cnt) return;
  const int nr = min(RPB, cnt - base);

  #pragma unroll
  for (int r = 0; r < RPB; r++)
    xs[r][threadIdx.x] = (r < nr) ? x[flags[base + r] * DIM + threadIdx.x] : 0.0f;
  __syncthreads();
  if (threadIdx.x < RPB) x2sh[threadIdx.x] = np_sumsq_256(xs[threadIdx.x]);
  __syncthreads();
  double x2d[RPB];
  #pragma unroll
  for (int r = 0; r < RPB; r++) x2d[r] = (double)x2sh[r];

  unsigned long long best[RPB];
  #pragma unroll
  for (int r = 0; r < RPB; r++) best[r] = ~0ULL;

  #pragma unroll 1
  for (int g = 0; g < 4; g++) {
    const int k = threadIdx.x * 4 + g;
    const float* wr = &w[k * DIM];
    const double w2 = (double)wnorm[k];
    double dot[RPB];
    #pragma unroll
    for (int r = 0; r < RPB; r++) dot[r] = 0.0;
    #pragma unroll 1
    for (int d = 0; d < DIM; d += 4) {
      const float4 wv = *(const float4*)&wr[d];
      #pragma unroll
      for (int r = 0; r < RPB; r++) {
        dot[r] = fma((double)xs[r][d],     (double)wv.x, dot[r]);
        dot[r] = fma((double)xs[r][d + 1], (double)wv.y, dot[r]);
        dot[r] = fma((double)xs[r][d + 2], (double)wv.z, dot[r]);
        dot[r] = fma((double)xs[r][d + 3], (double)wv.w, dot[r]);
      }
    }
    #pragma unroll
    for (int r = 0; r < RPB; r++) {
      const float mmf = (float)dot[r];                     // fl32(exact dot)
      const float S1  = (float)(x2d[r] + w2);              // fl32(x2 + w2)
      const float D   = (float)((double)S1 - 2.0 * (double)mmf); // fl32(S1-2mm)
      const unsigned long long key =
          ((unsigned long long)fkey(D) << 32) | (unsigned)k;
      if (key < best[r]) best[r] = key;
    }
  }

  #pragma unroll
  for (int r = 0; r < RPB; r++) red[r][threadIdx.x] = best[r];
  __syncthreads();
  #pragma unroll
  for (int off = 128; off > 0; off >>= 1) {
    if ((int)threadIdx.x < off) {
      #pragma unroll
      for (int r = 0; r < RPB; r++) {
        const unsigned long long o = red[r][threadIdx.x + off];
        if (o < red[r][threadIdx.x]) red[r][threadIdx.x] = o;
      }
    }
    __syncthreads();
  }
  if ((int)threadIdx.x < nr)
    idx[flags[base + threadIdx.x]] = (int)(red[threadIdx.x][0] & 0xffffffffULL);
}

// ---------------------------------------------------------------- counts ----
__global__ __launch_bounds__(256)
void counts_kernel(const int* __restrict__ idx, float* __restrict__ counts) {
  const int n = blockIdx.x * 256 + threadIdx.x;
  atomicAdd(&counts[idx[n]], 1.0f);
}

// -------------------------------------------------------------------- cs ----
__global__ __launch_bounds__(1024)
void cs_kernel(const float* __restrict__ ema_cs, const float* __restrict__ counts,
               float* __restrict__ out_cs, float* __restrict__ cs_ws) {
  __shared__ float lds[17];
  const int k = threadIdx.x;
  const float c = ema_cs[k] * 0.99f + 0.01f * counts[k];
  float v = c;
  #pragma unroll
  for (int off = 32; off > 0; off >>= 1) v += __shfl_down(v, off);
  if ((k & 63) == 0) lds[k >> 6] = v;
  __syncthreads();
  if (k == 0) {
    float n = 0.0f;
    for (int i = 0; i < 16; i++) n += lds[i];
    lds[16] = n;
  }
  __syncthreads();
  const float n = lds[16];
  const float csv = (c + 1e-5f) / (n + 1024.0f * 1e-5f) * n;
  out_cs[k] = csv;
  cs_ws[k]  = csv;
}

// ------------------------------------- fused quantize + loss + dw scatter ----
__global__ __launch_bounds__(256)
void quant_loss_dw_kernel(const float4* __restrict__ x4,
                          const float4* __restrict__ w4,
                          const int* __restrict__ idx,
                          float4* __restrict__ outq,
                          float* __restrict__ dw,
                          float* __restrict__ partials) {
  __shared__ float lds[4];
  const int g  = blockIdx.x * 256 + threadIdx.x;
  const int n  = g >> 6;
  const int d4 = g & 63;
  const float4 xv = x4[g];
  const int   k  = idx[n];
  const float4 qv = w4[k * 64 + d4];
  float4 r;
  r.x = xv.x + (qv.x - xv.x);
  r.y = xv.y + (qv.y - xv.y);
  r.z = xv.z + (qv.z - xv.z);
  r.w = xv.w + (qv.w - xv.w);
  outq[g] = r;

  float* dst = dw + k * DIM + d4 * 4;
  atomicAdd(dst + 0, xv.x);
  atomicAdd(dst + 1, xv.y);
  atomicAdd(dst + 2, xv.z);
  atomicAdd(dst + 3, xv.w);

  const float dx = xv.x - r.x, dy = xv.y - r.y, dz = xv.z - r.z, dwv = xv.w - r.w;
  float s = dx * dx + dy * dy + dz * dz + dwv * dwv;
  #pragma unroll
  for (int off = 32; off > 0; off >>= 1) s += __shfl_down(s, off);
  if ((threadIdx.x & 63) == 0) lds[threadIdx.x >> 6] = s;
  __syncthreads();
  if (threadIdx.x == 0) partials[blockIdx.x] = lds[0] + lds[1] + lds[2] + lds[3];
}

// ------------------------------------------------- ema_w_new + embed_new ----
__global__ __launch_bounds__(256)
void emb_kernel(const float* __restrict__ ema_w, const float* __restrict__ dw,
                const float* __restrict__ cs,
                float* __restrict__ out_ema_w, float* __restrict__ out_embed) {
  const int g = blockIdx.x * 256 + threadIdx.x;
  const int k = g >> 8;
  const float e = ema_w[g] * 0.99f + 0.01f * dw[g];
  out_ema_w[g] = e;
  out_embed[g] = e / cs[k];
}

// ---------------------------------------------------------- loss finalize ----
__global__ __launch_bounds__(256)
void loss_fin_kernel(const float* __restrict__ partials, float* __restrict__ out_loss) {
  __shared__ float lds[4];
  float s = 0.0f;
  for (int i = threadIdx.x; i < 4096; i += 256) s += partials[i];
  #pragma unroll
  for (int off = 32; off > 0; off >>= 1) s += __shfl_down(s, off);
  if ((threadIdx.x & 63) == 0) lds[threadIdx.x >> 6] = s;
  __syncthreads();
  if (threadIdx.x == 0) {
    const float total = lds[0] + lds[1] + lds[2] + lds[3];
    out_loss[0] = 0.25f * (total / 4194304.0f);
  }
}

// ------------------------------------------------------------------ launch ----
extern "C" void kernel_launch(void* const* d_in, const int* in_sizes, int n_in,
                              void* d_out, int out_size, void* d_ws, size_t ws_size,
                              hipStream_t stream) {
  const float* x       = (const float*)d_in[0];
  const float* embed_w = (const float*)d_in[1];
  const float* ema_cs  = (const float*)d_in[2];
  const float* ema_w   = (const float*)d_in[3];

  float* out        = (float*)d_out;
  float* out_q      = out;                 // 4194304
  float* out_loss   = out + 4194304;       // 1
  float* out_embed  = out + 4194305;       // 262144
  float* out_cs     = out + 4456449;       // 1024
  float* out_ema_w  = out + 4457473;       // 262144

  char* ws = (char*)d_ws;
  unsigned long long* pairs = (unsigned long long*)(ws + 0);   // 1048576 B
  int*   idx      = (int*)  (ws + 1048576);                    // 65536 B
  float* counts   = (float*)(ws + 1114112);                    // 4096 B
  float* dw       = (float*)(ws + 1118208);                    // 1048576 B
  float* cs_ws    = (float*)(ws + 2166784);                    // 4096 B
  float* wnorm    = (float*)(ws + 2170880);                    // 4096 B
  float* partials = (float*)(ws + 2174976);                    // 16384 B
  int*   flags    = (int*)  (ws + 2191360);                    // 32768 B
  int*   counter  = (int*)  (ws + 2224128);                    // 4 B

  hipMemsetAsync(counts, 0, 1052672, stream);   // counts + dw (contiguous)
  hipMemsetAsync(counter, 0, 4, stream);

  wnorm_np_kernel<<<KC / 256, 256, 0, stream>>>(embed_w, wnorm);
  dist_argmin_kernel<<<(NROW / MT) * KSPLIT, 256, 0, stream>>>(x, embed_w, wnorm, pairs);
  merge_kernel<<<NROW / 256, 256, 0, stream>>>(pairs, idx, flags, counter);
  recheck_np_kernel<<<FCAP / RPB, 256, 0, stream>>>(x, embed_w, wnorm, flags, counter, idx);
  counts_kernel<<<NROW / 256, 256, 0, stream>>>(idx, counts);
  cs_kernel<<<1, 1024, 0, stream>>>(ema_cs, counts, out_cs, cs_ws);
  quant_loss_dw_kernel<<<NROW * 64 / 256, 256, 0, stream>>>(
      (const float4*)x, (const float4*)embed_w, idx, (float4*)out_q, dw, partials);
  emb_kernel<<<KC * DIM / 256, 256, 0, stream>>>(ema_w, dw, cs_ws, out_ema_w, out_embed);
  loss_fin_kernel<<<1, 256, 0, stream>>>(partials, out_loss);
}

// Round 5
// 279.383 us; speedup vs baseline: 2.2882x; 1.3641x over previous
//
#include <hip/hip_runtime.h>
#include <cstdint>
#include <cstddef>

// Problem constants (B=16, T=1024, D=256, K=1024)
namespace {
constexpr int NROW = 16384;   // B*T
constexpr int KC   = 1024;    // codes
constexpr int DIM  = 256;
constexpr int MT   = 128;     // rows per block (argmin GEMM)
constexpr int KSPLIT = 4;     // codes partitioned across blocks
constexpr int KPB  = KC / KSPLIT;   // 256 codes per block
constexpr int FCAP = 8192;    // flagged-row capacity (expect ~450)
constexpr int RPB  = 4;       // flagged rows per recheck block
}

typedef __attribute__((ext_vector_type(8))) short bf16x8;
typedef __attribute__((ext_vector_type(4))) float f32x4;
typedef unsigned long long u64;

union U4 { uint32_t u[4]; bf16x8 v8; };

// Monotone float -> uint key (ascending), for packed argmin with index tie-break.
__device__ __forceinline__ unsigned fkey(float s) {
  unsigned u = __float_as_uint(s);
  return ((int)u >= 0) ? (u ^ 0x80000000u) : ~u;
}
__device__ __forceinline__ float unfkey(unsigned u) {
  return __uint_as_float((u & 0x80000000u) ? (u ^ 0x80000000u) : ~u);
}

// Split fp32 a into RNE-bf16 hi + RNE-bf16 of exact residual; pack lo16=hi.
__device__ __forceinline__ uint32_t splitpack(float a) {
  const uint32_t u  = __float_as_uint(a);
  const uint32_t rh = (u + 0x7fffu + ((u >> 16) & 1u)) >> 16;
  const float ah = __uint_as_float(rh << 16);
  const float al = a - ah;                      // exact (Sterbenz)
  const uint32_t v  = __float_as_uint(al);
  const uint32_t rl = (v + 0x7fffu + ((v >> 16) & 1u)) >> 16;
  return (rh & 0xffffu) | (rl << 16);
}

// numpy pairwise sum of squares of 256 floats, bit-exact emulation.
__device__ __forceinline__ float np_sumsq_256(const float* __restrict__ p) {
  float half[2];
  #pragma unroll
  for (int h = 0; h < 2; h++) {
    const float* q = p + h * 128;
    float r[8];
    #pragma unroll
    for (int j = 0; j < 8; j++) r[j] = __fmul_rn(q[j], q[j]);
    #pragma unroll 1
    for (int i = 8; i < 128; i += 8)
      #pragma unroll
      for (int j = 0; j < 8; j++)
        r[j] = __fadd_rn(r[j], __fmul_rn(q[i + j], q[i + j]));
    half[h] = __fadd_rn(__fadd_rn(__fadd_rn(r[0], r[1]), __fadd_rn(r[2], r[3])),
                        __fadd_rn(__fadd_rn(r[4], r[5]), __fadd_rn(r[6], r[7])));
  }
  return __fadd_rn(half[0], half[1]);
}

// ------------------------------------------------------------------ pack ----
// fp32 -> packed split-bf16 u32 for x (1048576 float4) and w (65536 float4).
__global__ __launch_bounds__(256)
void pack_kernel(const float4* __restrict__ x4, const float4* __restrict__ w4,
                 uint4* __restrict__ xpk, uint4* __restrict__ wpk) {
  const int g = blockIdx.x * 256 + threadIdx.x;
  float4 v; uint4* dst;
  if (g < 1048576) { v = x4[g]; dst = &xpk[g]; }
  else             { v = w4[g - 1048576]; dst = &wpk[g - 1048576]; }
  uint4 o;
  o.x = splitpack(v.x); o.y = splitpack(v.y);
  o.z = splitpack(v.z); o.w = splitpack(v.w);
  *dst = o;
}

// ---------------------------------------------------------------- wnorm ----
__global__ __launch_bounds__(256)
void wnorm_np_kernel(const float* __restrict__ w, float* __restrict__ wnorm) {
  const int k = blockIdx.x * 256 + threadIdx.x;   // grid = 4 blocks
  wnorm[k] = np_sumsq_256(&w[k * DIM]);
}

// ------------------------------------------- split-bf16 MFMA dist + top-2 ----
// Block: 128 rows x 256-code split; wave: 32 rows x 256 codes.
// dot = Ah*Bh + Ah*Bl + Al*Bh via mfma_f32_16x16x32_bf16 (error ~1e-6).
// LDS XOR-swizzled on 16B groups: elem (r,d) at col ((d>>2)^(r&7))*4+(d&3).
__global__ __launch_bounds__(256, 2)
void dist_mfma_kernel(const uint32_t* __restrict__ xpk,
                      const uint32_t* __restrict__ wpk,
                      const float* __restrict__ wnorm,
                      u64* __restrict__ pairs) {
  __shared__ uint32_t Alds[MT * 32];    // 16 KB
  __shared__ uint32_t Blds[KPB * 32];   // 32 KB

  const int tid  = threadIdx.x;
  const int lane = tid & 63;
  const int wv   = tid >> 6;
  const int quad = lane >> 4;
  const int idx16 = lane & 15;
  const int rowBase = (blockIdx.x >> 2) * MT;
  const int sp      = blockIdx.x & 3;
  const int kbase   = sp * KPB;

  f32x4 acc[2][16];
  #pragma unroll
  for (int rt = 0; rt < 2; rt++)
    #pragma unroll
    for (int ct = 0; ct < 16; ct++) acc[rt][ct] = (f32x4){0.f, 0.f, 0.f, 0.f};

  const int sr = tid >> 3;        // staging row group base
  const int sg = tid & 7;         // staging 16B-group
  const int spos = (sg ^ (sr & 7)) * 4;

  #pragma unroll 1
  for (int kc = 0; kc < DIM / 32; kc++) {
    const int dbase = kc * 32;
    __syncthreads();
    // stage A: 128 rows x 32 u32 (1024 uint4, 4/thread)
    #pragma unroll
    for (int i = 0; i < 4; i++) {
      const int r = sr + i * 32;
      const uint4 v = *(const uint4*)&xpk[(rowBase + r) * DIM + dbase + sg * 4];
      *(uint4*)&Alds[r * 32 + spos] = v;
    }
    // stage B: 256 rows x 32 u32 (2048 uint4, 8/thread)
    #pragma unroll
    for (int i = 0; i < 8; i++) {
      const int r = sr + i * 32;
      const uint4 v = *(const uint4*)&wpk[(kbase + r) * DIM + dbase + sg * 4];
      *(uint4*)&Blds[r * 32 + spos] = v;
    }
    __syncthreads();

    // A fragments for this wave's two 16-row tiles
    bf16x8 Ah[2], Al[2];
    #pragma unroll
    for (int rt = 0; rt < 2; rt++) {
      const int ar = wv * 32 + rt * 16 + idx16;
      const int p0 = (quad * 2) ^ (idx16 & 7);
      const uint4 q0 = *(const uint4*)&Alds[ar * 32 + p0 * 4];
      const uint4 q1 = *(const uint4*)&Alds[ar * 32 + (p0 ^ 1) * 4];
      U4 H, L;
      H.u[0] = (q0.x & 0xffffu) | (q0.y << 16);
      H.u[1] = (q0.z & 0xffffu) | (q0.w << 16);
      H.u[2] = (q1.x & 0xffffu) | (q1.y << 16);
      H.u[3] = (q1.z & 0xffffu) | (q1.w << 16);
      L.u[0] = (q0.x >> 16) | (q0.y & 0xffff0000u);
      L.u[1] = (q0.z >> 16) | (q0.w & 0xffff0000u);
      L.u[2] = (q1.x >> 16) | (q1.y & 0xffff0000u);
      L.u[3] = (q1.z >> 16) | (q1.w & 0xffff0000u);
      Ah[rt] = H.v8; Al[rt] = L.v8;
    }

    #pragma unroll
    for (int ct = 0; ct < 16; ct++) {
      const int br = ct * 16 + idx16;
      const int p0 = (quad * 2) ^ (idx16 & 7);
      const uint4 q0 = *(const uint4*)&Blds[br * 32 + p0 * 4];
      const uint4 q1 = *(const uint4*)&Blds[br * 32 + (p0 ^ 1) * 4];
      U4 H, L;
      H.u[0] = (q0.x & 0xffffu) | (q0.y << 16);
      H.u[1] = (q0.z & 0xffffu) | (q0.w << 16);
      H.u[2] = (q1.x & 0xffffu) | (q1.y << 16);
      H.u[3] = (q1.z & 0xffffu) | (q1.w << 16);
      L.u[0] = (q0.x >> 16) | (q0.y & 0xffff0000u);
      L.u[1] = (q0.z >> 16) | (q0.w & 0xffff0000u);
      L.u[2] = (q1.x >> 16) | (q1.y & 0xffff0000u);
      L.u[3] = (q1.z >> 16) | (q1.w & 0xffff0000u);
      const bf16x8 Bh = H.v8, Bl = L.v8;
      #pragma unroll
      for (int rt = 0; rt < 2; rt++) {
        acc[rt][ct] = __builtin_amdgcn_mfma_f32_16x16x32_bf16(Al[rt], Bh, acc[rt][ct], 0, 0, 0);
        acc[rt][ct] = __builtin_amdgcn_mfma_f32_16x16x32_bf16(Ah[rt], Bl, acc[rt][ct], 0, 0, 0);
        acc[rt][ct] = __builtin_amdgcn_mfma_f32_16x16x32_bf16(Ah[rt], Bh, acc[rt][ct], 0, 0, 0);
      }
    }
  }

  // Epilogue: score = wnorm - 2*dot; per-lane top-2 across 16 col-tiles,
  // then 4-stage butterfly across the 16 cols (lanes within a quad-group).
  u64 b0[2][4], b1[2][4];
  #pragma unroll
  for (int rt = 0; rt < 2; rt++)
    #pragma unroll
    for (int reg = 0; reg < 4; reg++) { b0[rt][reg] = ~0ULL; b1[rt][reg] = ~0ULL; }

  #pragma unroll
  for (int ct = 0; ct < 16; ct++) {
    const int col = kbase + ct * 16 + idx16;
    const float wn = wnorm[col];
    #pragma unroll
    for (int rt = 0; rt < 2; rt++) {
      #pragma unroll
      for (int reg = 0; reg < 4; reg++) {
        const float s = fmaf(-2.0f, acc[rt][ct][reg], wn);
        const u64 p = ((u64)fkey(s) << 32) | (unsigned)col;
        if (p < b1[rt][reg]) {
          if (p < b0[rt][reg]) { b1[rt][reg] = b0[rt][reg]; b0[rt][reg] = p; }
          else                 { b1[rt][reg] = p; }
        }
      }
    }
  }

  #pragma unroll
  for (int m = 1; m <= 8; m <<= 1) {
    #pragma unroll
    for (int rt = 0; rt < 2; rt++) {
      #pragma unroll
      for (int reg = 0; reg < 4; reg++) {
        const u64 o0 = __shfl_xor(b0[rt][reg], m);
        const u64 o1 = __shfl_xor(b1[rt][reg], m);
        if (o0 < b0[rt][reg]) {
          b1[rt][reg] = (b0[rt][reg] < o1) ? b0[rt][reg] : o1;
          b0[rt][reg] = o0;
        } else {
          b1[rt][reg] = (b1[rt][reg] < o0) ? b1[rt][reg] : o0;
        }
      }
    }
  }

  if (idx16 == 0) {
    #pragma unroll
    for (int rt = 0; rt < 2; rt++) {
      #pragma unroll
      for (int reg = 0; reg < 4; reg++) {
        const int row = rowBase + wv * 32 + rt * 16 + quad * 4 + reg;
        pairs[row * 8 + sp * 2 + 0] = b0[rt][reg];
        pairs[row * 8 + sp * 2 + 1] = b1[rt][reg];
      }
    }
  }
}

// ------------------------------------- merge splits + flag + counts ----
__global__ __launch_bounds__(256)
void merge_kernel(const u64* __restrict__ pairs,
                  int* __restrict__ idx, float* __restrict__ counts,
                  int* __restrict__ flags, int* __restrict__ counter) {
  const int row = blockIdx.x * 256 + threadIdx.x;
  const u64* p = &pairs[row * 8];
  u64 B0 = p[0], B1 = p[1];
  #pragma unroll
  for (int s = 1; s < KSPLIT; s++) {
    const u64 c0 = p[s * 2], c1 = p[s * 2 + 1];
    if (c0 < B0) { B1 = (B0 < c1) ? B0 : c1; B0 = c0; }
    else         { B1 = (B1 < c0) ? B1 : c0; }
  }
  const int k = (int)(B0 & 0xffffffffULL);
  idx[row] = k;
  atomicAdd(&counts[k], 1.0f);
  const float s0 = unfkey((unsigned)(B0 >> 32));
  const float s1 = unfkey((unsigned)(B1 >> 32));
  if (s1 - s0 < 2e-4f) {
    const int pos = atomicAdd(counter, 1);
    if (pos < FCAP) flags[pos] = row;
  }
}

// --------------------- np-fp32-emulating recheck; adjusts counts on flips ----
__global__ __launch_bounds__(256)
void recheck_np_kernel(const float* __restrict__ x, const float* __restrict__ w,
                       const float* __restrict__ wnorm,
                       const int* __restrict__ flags, const int* __restrict__ counter,
                       int* __restrict__ idx, float* __restrict__ counts) {
  __shared__ float xs[RPB][DIM];
  __shared__ float x2sh[RPB];
  __shared__ u64 red[RPB][256];

  const int cnt  = min(*counter, FCAP);
  const int base = blockIdx.x * RPB;
  if (base >= cnt) return;
  const int nr = min(RPB, cnt - base);

  #pragma unroll
  for (int r = 0; r < RPB; r++)
    xs[r][threadIdx.x] = (r < nr) ? x[flags[base + r] * DIM + threadIdx.x] : 0.0f;
  __syncthreads();
  if (threadIdx.x < RPB) x2sh[threadIdx.x] = np_sumsq_256(xs[threadIdx.x]);
  __syncthreads();
  double x2d[RPB];
  #pragma unroll
  for (int r = 0; r < RPB; r++) x2d[r] = (double)x2sh[r];

  u64 best[RPB];
  #pragma unroll
  for (int r = 0; r < RPB; r++) best[r] = ~0ULL;

  #pragma unroll 1
  for (int g = 0; g < 4; g++) {
    const int k = threadIdx.x * 4 + g;
    const float* wr = &w[k * DIM];
    const double w2 = (double)wnorm[k];
    double dot[RPB];
    #pragma unroll
    for (int r = 0; r < RPB; r++) dot[r] = 0.0;
    #pragma unroll 1
    for (int d = 0; d < DIM; d += 4) {
      const float4 wv = *(const float4*)&wr[d];
      #pragma unroll
      for (int r = 0; r < RPB; r++) {
        dot[r] = fma((double)xs[r][d],     (double)wv.x, dot[r]);
        dot[r] = fma((double)xs[r][d + 1], (double)wv.y, dot[r]);
        dot[r] = fma((double)xs[r][d + 2], (double)wv.z, dot[r]);
        dot[r] = fma((double)xs[r][d + 3], (double)wv.w, dot[r]);
      }
    }
    #pragma unroll
    for (int r = 0; r < RPB; r++) {
      const float mmf = (float)dot[r];
      const float S1  = (float)(x2d[r] + w2);
      const float D   = (float)((double)S1 - 2.0 * (double)mmf);
      const u64 key = ((u64)fkey(D) << 32) | (unsigned)k;
      if (key < best[r]) best[r] = key;
    }
  }

  #pragma unroll
  for (int r = 0; r < RPB; r++) red[r][threadIdx.x] = best[r];
  __syncthreads();
  #pragma unroll
  for (int off = 128; off > 0; off >>= 1) {
    if ((int)threadIdx.x < off) {
      #pragma unroll
      for (int r = 0; r < RPB; r++) {
        const u64 o = red[r][threadIdx.x + off];
        if (o < red[r][threadIdx.x]) red[r][threadIdx.x] = o;
      }
    }
    __syncthreads();
  }
  if ((int)threadIdx.x < nr) {
    const int row  = flags[base + threadIdx.x];
    const int newk = (int)(red[threadIdx.x][0] & 0xffffffffULL);
    const int oldk = idx[row];
    if (newk != oldk) {
      idx[row] = newk;
      atomicAdd(&counts[newk],  1.0f);
      atomicAdd(&counts[oldk], -1.0f);
    }
  }
}

// -------------------------------------------------------------------- cs ----
__global__ __launch_bounds__(1024)
void cs_kernel(const float* __restrict__ ema_cs, const float* __restrict__ counts,
               float* __restrict__ out_cs, float* __restrict__ cs_ws) {
  __shared__ float lds[17];
  const int k = threadIdx.x;
  const float c = ema_cs[k] * 0.99f + 0.01f * counts[k];
  float v = c;
  #pragma unroll
  for (int off = 32; off > 0; off >>= 1) v += __shfl_down(v, off);
  if ((k & 63) == 0) lds[k >> 6] = v;
  __syncthreads();
  if (k == 0) {
    float n = 0.0f;
    for (int i = 0; i < 16; i++) n += lds[i];
    lds[16] = n;
  }
  __syncthreads();
  const float n = lds[16];
  const float csv = (c + 1e-5f) / (n + 1024.0f * 1e-5f) * n;
  out_cs[k] = csv;
  cs_ws[k]  = csv;
}

// ------------------------------------- fused quantize + loss + dw scatter ----
__global__ __launch_bounds__(256)
void quant_loss_dw_kernel(const float4* __restrict__ x4,
                          const float4* __restrict__ w4,
                          const int* __restrict__ idx,
                          float4* __restrict__ outq,
                          float* __restrict__ dw,
                          float* __restrict__ partials) {
  __shared__ float lds[4];
  const int g  = blockIdx.x * 256 + threadIdx.x;
  const int n  = g >> 6;
  const int d4 = g & 63;
  const float4 xv = x4[g];
  const int   k  = idx[n];
  const float4 qv = w4[k * 64 + d4];
  float4 r;
  r.x = xv.x + (qv.x - xv.x);
  r.y = xv.y + (qv.y - xv.y);
  r.z = xv.z + (qv.z - xv.z);
  r.w = xv.w + (qv.w - xv.w);
  outq[g] = r;

  float* dst = dw + k * DIM + d4 * 4;
  atomicAdd(dst + 0, xv.x);
  atomicAdd(dst + 1, xv.y);
  atomicAdd(dst + 2, xv.z);
  atomicAdd(dst + 3, xv.w);

  const float dx = xv.x - r.x, dy = xv.y - r.y, dz = xv.z - r.z, dwv = xv.w - r.w;
  float s = dx * dx + dy * dy + dz * dz + dwv * dwv;
  #pragma unroll
  for (int off = 32; off > 0; off >>= 1) s += __shfl_down(s, off);
  if ((threadIdx.x & 63) == 0) lds[threadIdx.x >> 6] = s;
  __syncthreads();
  if (threadIdx.x == 0) partials[blockIdx.x] = lds[0] + lds[1] + lds[2] + lds[3];
}

// ------------------------------------------------- ema_w_new + embed_new ----
__global__ __launch_bounds__(256)
void emb_kernel(const float* __restrict__ ema_w, const float* __restrict__ dw,
                const float* __restrict__ cs,
                float* __restrict__ out_ema_w, float* __restrict__ out_embed) {
  const int g = blockIdx.x * 256 + threadIdx.x;
  const int k = g >> 8;
  const float e = ema_w[g] * 0.99f + 0.01f * dw[g];
  out_ema_w[g] = e;
  out_embed[g] = e / cs[k];
}

// ---------------------------------------------------------- loss finalize ----
__global__ __launch_bounds__(256)
void loss_fin_kernel(const float* __restrict__ partials, float* __restrict__ out_loss) {
  __shared__ float lds[4];
  float s = 0.0f;
  for (int i = threadIdx.x; i < 4096; i += 256) s += partials[i];
  #pragma unroll
  for (int off = 32; off > 0; off >>= 1) s += __shfl_down(s, off);
  if ((threadIdx.x & 63) == 0) lds[threadIdx.x >> 6] = s;
  __syncthreads();
  if (threadIdx.x == 0) {
    const float total = lds[0] + lds[1] + lds[2] + lds[3];
    out_loss[0] = 0.25f * (total / 4194304.0f);
  }
}

// ------------------------------------------------------------------ launch ----
extern "C" void kernel_launch(void* const* d_in, const int* in_sizes, int n_in,
                              void* d_out, int out_size, void* d_ws, size_t ws_size,
                              hipStream_t stream) {
  const float* x       = (const float*)d_in[0];
  const float* embed_w = (const float*)d_in[1];
  const float* ema_cs  = (const float*)d_in[2];
  const float* ema_w   = (const float*)d_in[3];

  float* out        = (float*)d_out;
  float* out_q      = out;                 // 4194304
  float* out_loss   = out + 4194304;       // 1
  float* out_embed  = out + 4194305;       // 262144
  float* out_cs     = out + 4456449;       // 1024
  float* out_ema_w  = out + 4457473;       // 262144

  char* ws = (char*)d_ws;
  u64*   pairs    = (u64*)  (ws + 0);                          // 1048576 B
  int*   idx      = (int*)  (ws + 1048576);                    // 65536 B
  float* counts   = (float*)(ws + 1114112);                    // 4096 B
  float* dw       = (float*)(ws + 1118208);                    // 1048576 B (also wpk)
  float* cs_ws    = (float*)(ws + 2166784);                    // 4096 B
  float* wnorm    = (float*)(ws + 2170880);                    // 4096 B
  float* partials = (float*)(ws + 2174976);                    // 16384 B
  int*   flags    = (int*)  (ws + 2191360);                    // 32768 B
  int*   counter  = (int*)  (ws + 2224128);                    // 4 B

  // xpk aliases out_q (16 MB, overwritten by quant later); wpk aliases dw
  // (dw memset deferred until after dist has consumed wpk).
  uint32_t* xpk = (uint32_t*)out_q;
  uint32_t* wpk = (uint32_t*)dw;

  hipMemsetAsync(counts, 0, 4096, stream);
  hipMemsetAsync(counter, 0, 4, stream);

  pack_kernel<<<4352, 256, 0, stream>>>((const float4*)x, (const float4*)embed_w,
                                        (uint4*)xpk, (uint4*)wpk);
  wnorm_np_kernel<<<KC / 256, 256, 0, stream>>>(embed_w, wnorm);
  dist_mfma_kernel<<<(NROW / MT) * KSPLIT, 256, 0, stream>>>(xpk, wpk, wnorm, pairs);
  merge_kernel<<<NROW / 256, 256, 0, stream>>>(pairs, idx, counts, flags, counter);
  recheck_np_kernel<<<FCAP / RPB, 256, 0, stream>>>(x, embed_w, wnorm, flags, counter,
                                                    idx, counts);
  hipMemsetAsync(dw, 0, 1048576, stream);   // after dist consumed wpk
  cs_kernel<<<1, 1024, 0, stream>>>(ema_cs, counts, out_cs, cs_ws);
  quant_loss_dw_kernel<<<NROW * 64 / 256, 256, 0, stream>>>(
      (const float4*)x, (const float4*)embed_w, idx, (float4*)out_q, dw, partials);
  emb_kernel<<<KC * DIM / 256, 256, 0, stream>>>(ema_w, dw, cs_ws, out_ema_w, out_embed);
  loss_fin_kernel<<<1, 256, 0, stream>>>(partials, out_loss);
}

// Round 6
// 238.374 us; speedup vs baseline: 2.6819x; 1.1720x over previous
//
#include <hip/hip_runtime.h>
#include <cstdint>
#include <cstddef>

// Problem constants (B=16, T=1024, D=256, K=1024)
namespace {
constexpr int NROW = 16384;   // B*T
constexpr int KC   = 1024;    // codes
constexpr int DIM  = 256;
constexpr int MT   = 128;     // rows per block (argmin GEMM)
constexpr int KSPLIT = 4;     // codes partitioned across blocks
constexpr int KPB  = KC / KSPLIT;   // 256 codes per block
constexpr int FCAP = 8192;    // flagged-row capacity (expect ~450)
constexpr int RPB  = 4;       // flagged rows per recheck block
}

typedef __attribute__((ext_vector_type(8))) short bf16x8;
typedef __attribute__((ext_vector_type(4))) float f32x4;
typedef unsigned long long u64;

union U4 { uint32_t u[4]; bf16x8 v8; };

// Monotone float -> uint key (ascending), for packed argmin with index tie-break.
__device__ __forceinline__ unsigned fkey(float s) {
  unsigned u = __float_as_uint(s);
  return ((int)u >= 0) ? (u ^ 0x80000000u) : ~u;
}
__device__ __forceinline__ float unfkey(unsigned u) {
  return __uint_as_float((u & 0x80000000u) ? (u ^ 0x80000000u) : ~u);
}

// Split fp32 a into RNE-bf16 hi + RNE-bf16 of exact residual; pack lo16=hi.
__device__ __forceinline__ uint32_t splitpack(float a) {
  const uint32_t u  = __float_as_uint(a);
  const uint32_t rh = (u + 0x7fffu + ((u >> 16) & 1u)) >> 16;
  const float ah = __uint_as_float(rh << 16);
  const float al = a - ah;                      // exact (Sterbenz)
  const uint32_t v  = __float_as_uint(al);
  const uint32_t rl = (v + 0x7fffu + ((v >> 16) & 1u)) >> 16;
  return (rh & 0xffffu) | (rl << 16);
}

// numpy pairwise sum of squares of 256 floats, bit-exact emulation.
__device__ __forceinline__ float np_sumsq_256(const float* __restrict__ p) {
  float half[2];
  #pragma unroll
  for (int h = 0; h < 2; h++) {
    const float* q = p + h * 128;
    float r[8];
    #pragma unroll
    for (int j = 0; j < 8; j++) r[j] = __fmul_rn(q[j], q[j]);
    #pragma unroll 1
    for (int i = 8; i < 128; i += 8)
      #pragma unroll
      for (int j = 0; j < 8; j++)
        r[j] = __fadd_rn(r[j], __fmul_rn(q[i + j], q[i + j]));
    half[h] = __fadd_rn(__fadd_rn(__fadd_rn(r[0], r[1]), __fadd_rn(r[2], r[3])),
                        __fadd_rn(__fadd_rn(r[4], r[5]), __fadd_rn(r[6], r[7])));
  }
  return __fadd_rn(half[0], half[1]);
}

// ------------------------------------------------------------------ pack ----
__global__ __launch_bounds__(256)
void pack_kernel(const float4* __restrict__ x4, const float4* __restrict__ w4,
                 uint4* __restrict__ xpk, uint4* __restrict__ wpk) {
  const int g = blockIdx.x * 256 + threadIdx.x;
  float4 v; uint4* dst;
  if (g < 1048576) { v = x4[g]; dst = &xpk[g]; }
  else             { v = w4[g - 1048576]; dst = &wpk[g - 1048576]; }
  uint4 o;
  o.x = splitpack(v.x); o.y = splitpack(v.y);
  o.z = splitpack(v.z); o.w = splitpack(v.w);
  *dst = o;
}

// ---------------------------------------------------------------- wnorm ----
__global__ __launch_bounds__(256)
void wnorm_np_kernel(const float* __restrict__ w, float* __restrict__ wnorm) {
  const int k = blockIdx.x * 256 + threadIdx.x;   // grid = 4 blocks
  wnorm[k] = np_sumsq_256(&w[k * DIM]);
}

// ------------------------------------------- split-bf16 MFMA dist + top-2 ----
__global__ __launch_bounds__(256, 2)
void dist_mfma_kernel(const uint32_t* __restrict__ xpk,
                      const uint32_t* __restrict__ wpk,
                      const float* __restrict__ wnorm,
                      u64* __restrict__ pairs) {
  __shared__ uint32_t Alds[MT * 32];    // 16 KB
  __shared__ uint32_t Blds[KPB * 32];   // 32 KB

  const int tid  = threadIdx.x;
  const int lane = tid & 63;
  const int wv   = tid >> 6;
  const int quad = lane >> 4;
  const int idx16 = lane & 15;
  const int rowBase = (blockIdx.x >> 2) * MT;
  const int sp      = blockIdx.x & 3;
  const int kbase   = sp * KPB;

  f32x4 acc[2][16];
  #pragma unroll
  for (int rt = 0; rt < 2; rt++)
    #pragma unroll
    for (int ct = 0; ct < 16; ct++) acc[rt][ct] = (f32x4){0.f, 0.f, 0.f, 0.f};

  const int sr = tid >> 3;        // staging row group base
  const int sg = tid & 7;         // staging 16B-group
  const int spos = (sg ^ (sr & 7)) * 4;

  #pragma unroll 1
  for (int kc = 0; kc < DIM / 32; kc++) {
    const int dbase = kc * 32;
    __syncthreads();
    #pragma unroll
    for (int i = 0; i < 4; i++) {
      const int r = sr + i * 32;
      const uint4 v = *(const uint4*)&xpk[(rowBase + r) * DIM + dbase + sg * 4];
      *(uint4*)&Alds[r * 32 + spos] = v;
    }
    #pragma unroll
    for (int i = 0; i < 8; i++) {
      const int r = sr + i * 32;
      const uint4 v = *(const uint4*)&wpk[(kbase + r) * DIM + dbase + sg * 4];
      *(uint4*)&Blds[r * 32 + spos] = v;
    }
    __syncthreads();

    bf16x8 Ah[2], Al[2];
    #pragma unroll
    for (int rt = 0; rt < 2; rt++) {
      const int ar = wv * 32 + rt * 16 + idx16;
      const int p0 = (quad * 2) ^ (idx16 & 7);
      const uint4 q0 = *(const uint4*)&Alds[ar * 32 + p0 * 4];
      const uint4 q1 = *(const uint4*)&Alds[ar * 32 + (p0 ^ 1) * 4];
      U4 H, L;
      H.u[0] = (q0.x & 0xffffu) | (q0.y << 16);
      H.u[1] = (q0.z & 0xffffu) | (q0.w << 16);
      H.u[2] = (q1.x & 0xffffu) | (q1.y << 16);
      H.u[3] = (q1.z & 0xffffu) | (q1.w << 16);
      L.u[0] = (q0.x >> 16) | (q0.y & 0xffff0000u);
      L.u[1] = (q0.z >> 16) | (q0.w & 0xffff0000u);
      L.u[2] = (q1.x >> 16) | (q1.y & 0xffff0000u);
      L.u[3] = (q1.z >> 16) | (q1.w & 0xffff0000u);
      Ah[rt] = H.v8; Al[rt] = L.v8;
    }

    #pragma unroll
    for (int ct = 0; ct < 16; ct++) {
      const int br = ct * 16 + idx16;
      const int p0 = (quad * 2) ^ (idx16 & 7);
      const uint4 q0 = *(const uint4*)&Blds[br * 32 + p0 * 4];
      const uint4 q1 = *(const uint4*)&Blds[br * 32 + (p0 ^ 1) * 4];
      U4 H, L;
      H.u[0] = (q0.x & 0xffffu) | (q0.y << 16);
      H.u[1] = (q0.z & 0xffffu) | (q0.w << 16);
      H.u[2] = (q1.x & 0xffffu) | (q1.y << 16);
      H.u[3] = (q1.z & 0xffffu) | (q1.w << 16);
      L.u[0] = (q0.x >> 16) | (q0.y & 0xffff0000u);
      L.u[1] = (q0.z >> 16) | (q0.w & 0xffff0000u);
      L.u[2] = (q1.x >> 16) | (q1.y & 0xffff0000u);
      L.u[3] = (q1.z >> 16) | (q1.w & 0xffff0000u);
      const bf16x8 Bh = H.v8, Bl = L.v8;
      #pragma unroll
      for (int rt = 0; rt < 2; rt++) {
        acc[rt][ct] = __builtin_amdgcn_mfma_f32_16x16x32_bf16(Al[rt], Bh, acc[rt][ct], 0, 0, 0);
        acc[rt][ct] = __builtin_amdgcn_mfma_f32_16x16x32_bf16(Ah[rt], Bl, acc[rt][ct], 0, 0, 0);
        acc[rt][ct] = __builtin_amdgcn_mfma_f32_16x16x32_bf16(Ah[rt], Bh, acc[rt][ct], 0, 0, 0);
      }
    }
  }

  u64 b0[2][4], b1[2][4];
  #pragma unroll
  for (int rt = 0; rt < 2; rt++)
    #pragma unroll
    for (int reg = 0; reg < 4; reg++) { b0[rt][reg] = ~0ULL; b1[rt][reg] = ~0ULL; }

  #pragma unroll
  for (int ct = 0; ct < 16; ct++) {
    const int col = kbase + ct * 16 + idx16;
    const float wn = wnorm[col];
    #pragma unroll
    for (int rt = 0; rt < 2; rt++) {
      #pragma unroll
      for (int reg = 0; reg < 4; reg++) {
        const float s = fmaf(-2.0f, acc[rt][ct][reg], wn);
        const u64 p = ((u64)fkey(s) << 32) | (unsigned)col;
        if (p < b1[rt][reg]) {
          if (p < b0[rt][reg]) { b1[rt][reg] = b0[rt][reg]; b0[rt][reg] = p; }
          else                 { b1[rt][reg] = p; }
        }
      }
    }
  }

  #pragma unroll
  for (int m = 1; m <= 8; m <<= 1) {
    #pragma unroll
    for (int rt = 0; rt < 2; rt++) {
      #pragma unroll
      for (int reg = 0; reg < 4; reg++) {
        const u64 o0 = __shfl_xor(b0[rt][reg], m);
        const u64 o1 = __shfl_xor(b1[rt][reg], m);
        if (o0 < b0[rt][reg]) {
          b1[rt][reg] = (b0[rt][reg] < o1) ? b0[rt][reg] : o1;
          b0[rt][reg] = o0;
        } else {
          b1[rt][reg] = (b1[rt][reg] < o0) ? b1[rt][reg] : o0;
        }
      }
    }
  }

  if (idx16 == 0) {
    #pragma unroll
    for (int rt = 0; rt < 2; rt++) {
      #pragma unroll
      for (int reg = 0; reg < 4; reg++) {
        const int row = rowBase + wv * 32 + rt * 16 + quad * 4 + reg;
        pairs[row * 8 + sp * 2 + 0] = b0[rt][reg];
        pairs[row * 8 + sp * 2 + 1] = b1[rt][reg];
      }
    }
  }
}

// ------------------------------------- merge splits + flag + counts ----
__global__ __launch_bounds__(256)
void merge_kernel(const u64* __restrict__ pairs,
                  int* __restrict__ idx, float* __restrict__ counts,
                  int* __restrict__ flags, int* __restrict__ counter) {
  const int row = blockIdx.x * 256 + threadIdx.x;
  const u64* p = &pairs[row * 8];
  u64 B0 = p[0], B1 = p[1];
  #pragma unroll
  for (int s = 1; s < KSPLIT; s++) {
    const u64 c0 = p[s * 2], c1 = p[s * 2 + 1];
    if (c0 < B0) { B1 = (B0 < c1) ? B0 : c1; B0 = c0; }
    else         { B1 = (B1 < c0) ? B1 : c0; }
  }
  const int k = (int)(B0 & 0xffffffffULL);
  idx[row] = k;
  atomicAdd(&counts[k], 1.0f);
  const float s0 = unfkey((unsigned)(B0 >> 32));
  const float s1 = unfkey((unsigned)(B1 >> 32));
  if (s1 - s0 < 2e-4f) {
    const int pos = atomicAdd(counter, 1);
    if (pos < FCAP) flags[pos] = row;
  }
}

// --------------------- np-fp32-emulating recheck; adjusts counts on flips ----
__global__ __launch_bounds__(256)
void recheck_np_kernel(const float* __restrict__ x, const float* __restrict__ w,
                       const float* __restrict__ wnorm,
                       const int* __restrict__ flags, const int* __restrict__ counter,
                       int* __restrict__ idx, float* __restrict__ counts) {
  __shared__ float xs[RPB][DIM];
  __shared__ float x2sh[RPB];
  __shared__ u64 red[RPB][256];

  const int cnt  = min(*counter, FCAP);
  const int base = blockIdx.x * RPB;
  if (base >= cnt) return;
  const int nr = min(RPB, cnt - base);

  #pragma unroll
  for (int r = 0; r < RPB; r++)
    xs[r][threadIdx.x] = (r < nr) ? x[flags[base + r] * DIM + threadIdx.x] : 0.0f;
  __syncthreads();
  if (threadIdx.x < RPB) x2sh[threadIdx.x] = np_sumsq_256(xs[threadIdx.x]);
  __syncthreads();
  double x2d[RPB];
  #pragma unroll
  for (int r = 0; r < RPB; r++) x2d[r] = (double)x2sh[r];

  u64 best[RPB];
  #pragma unroll
  for (int r = 0; r < RPB; r++) best[r] = ~0ULL;

  #pragma unroll 1
  for (int g = 0; g < 4; g++) {
    const int k = threadIdx.x * 4 + g;
    const float* wr = &w[k * DIM];
    const double w2 = (double)wnorm[k];
    double dot[RPB];
    #pragma unroll
    for (int r = 0; r < RPB; r++) dot[r] = 0.0;
    #pragma unroll 1
    for (int d = 0; d < DIM; d += 4) {
      const float4 wv = *(const float4*)&wr[d];
      #pragma unroll
      for (int r = 0; r < RPB; r++) {
        dot[r] = fma((double)xs[r][d],     (double)wv.x, dot[r]);
        dot[r] = fma((double)xs[r][d + 1], (double)wv.y, dot[r]);
        dot[r] = fma((double)xs[r][d + 2], (double)wv.z, dot[r]);
        dot[r] = fma((double)xs[r][d + 3], (double)wv.w, dot[r]);
      }
    }
    #pragma unroll
    for (int r = 0; r < RPB; r++) {
      const float mmf = (float)dot[r];
      const float S1  = (float)(x2d[r] + w2);
      const float D   = (float)((double)S1 - 2.0 * (double)mmf);
      const u64 key = ((u64)fkey(D) << 32) | (unsigned)k;
      if (key < best[r]) best[r] = key;
    }
  }

  #pragma unroll
  for (int r = 0; r < RPB; r++) red[r][threadIdx.x] = best[r];
  __syncthreads();
  #pragma unroll
  for (int off = 128; off > 0; off >>= 1) {
    if ((int)threadIdx.x < off) {
      #pragma unroll
      for (int r = 0; r < RPB; r++) {
        const u64 o = red[r][threadIdx.x + off];
        if (o < red[r][threadIdx.x]) red[r][threadIdx.x] = o;
      }
    }
    __syncthreads();
  }
  if ((int)threadIdx.x < nr) {
    const int row  = flags[base + threadIdx.x];
    const int newk = (int)(red[threadIdx.x][0] & 0xffffffffULL);
    const int oldk = idx[row];
    if (newk != oldk) {
      idx[row] = newk;
      atomicAdd(&counts[newk],  1.0f);
      atomicAdd(&counts[oldk], -1.0f);
    }
  }
}

// ----------------------------------------------- prefix scan over counts ----
// starts[k] = exclusive prefix of (int)counts[k]; cursor[k] = starts[k].
__global__ __launch_bounds__(1024)
void prefix_kernel(const float* __restrict__ counts,
                   int* __restrict__ starts, int* __restrict__ cursor) {
  __shared__ int sc[1024];
  const int t = threadIdx.x;
  const int c = (int)counts[t];
  sc[t] = c;
  __syncthreads();
  #pragma unroll
  for (int off = 1; off < 1024; off <<= 1) {
    const int v = (t >= off) ? sc[t - off] : 0;
    __syncthreads();
    sc[t] += v;
    __syncthreads();
  }
  const int excl = sc[t] - c;
  starts[t] = excl;
  cursor[t] = excl;
}

// ------------------------------------------------------ bucket scatter ----
__global__ __launch_bounds__(256)
void scatter_kernel(const int* __restrict__ idx, int* __restrict__ cursor,
                    int* __restrict__ bucket) {
  const int row = blockIdx.x * 256 + threadIdx.x;
  const int k = idx[row];
  const int pos = atomicAdd(&cursor[k], 1);
  bucket[pos] = row;
}

// ----------------------------------- per-cluster dw reduction (no atomics) ----
// One block per cluster: 64 lanes (float4 over D) x 4 row-groups.
__global__ __launch_bounds__(256)
void dw_bucket_kernel(const float4* __restrict__ x4, const int* __restrict__ bucket,
                      const int* __restrict__ starts, const float* __restrict__ counts,
                      float4* __restrict__ dw4) {
  __shared__ float4 red[4][64];
  const int k   = blockIdx.x;
  const int d4  = threadIdx.x & 63;
  const int rg  = threadIdx.x >> 6;
  const int s   = starts[k];
  const int e   = s + (int)counts[k];
  float4 acc = {0.f, 0.f, 0.f, 0.f};
  for (int i = s + rg; i < e; i += 4) {
    const float4 v = x4[bucket[i] * 64 + d4];
    acc.x += v.x; acc.y += v.y; acc.z += v.z; acc.w += v.w;
  }
  red[rg][d4] = acc;
  __syncthreads();
  if (rg == 0) {
    const float4 a1 = red[1][d4], a2 = red[2][d4], a3 = red[3][d4];
    acc.x += a1.x + a2.x + a3.x;
    acc.y += a1.y + a2.y + a3.y;
    acc.z += a1.z + a2.z + a3.z;
    acc.w += a1.w + a2.w + a3.w;
    dw4[k * 64 + d4] = acc;
  }
}

// -------------------------------------------------------------------- cs ----
__global__ __launch_bounds__(1024)
void cs_kernel(const float* __restrict__ ema_cs, const float* __restrict__ counts,
               float* __restrict__ out_cs, float* __restrict__ cs_ws) {
  __shared__ float lds[17];
  const int k = threadIdx.x;
  const float c = ema_cs[k] * 0.99f + 0.01f * counts[k];
  float v = c;
  #pragma unroll
  for (int off = 32; off > 0; off >>= 1) v += __shfl_down(v, off);
  if ((k & 63) == 0) lds[k >> 6] = v;
  __syncthreads();
  if (k == 0) {
    float n = 0.0f;
    for (int i = 0; i < 16; i++) n += lds[i];
    lds[16] = n;
  }
  __syncthreads();
  const float n = lds[16];
  const float csv = (c + 1e-5f) / (n + 1024.0f * 1e-5f) * n;
  out_cs[k] = csv;
  cs_ws[k]  = csv;
}

// ------------------------------------------- quantize + loss (no atomics) ----
__global__ __launch_bounds__(256)
void quant_loss_kernel(const float4* __restrict__ x4,
                       const float4* __restrict__ w4,
                       const int* __restrict__ idx,
                       float4* __restrict__ outq,
                       float* __restrict__ partials) {
  __shared__ float lds[4];
  const int g  = blockIdx.x * 256 + threadIdx.x;
  const int n  = g >> 6;
  const int d4 = g & 63;
  const float4 xv = x4[g];
  const int   k  = idx[n];
  const float4 qv = w4[k * 64 + d4];
  float4 r;
  r.x = xv.x + (qv.x - xv.x);
  r.y = xv.y + (qv.y - xv.y);
  r.z = xv.z + (qv.z - xv.z);
  r.w = xv.w + (qv.w - xv.w);
  outq[g] = r;

  const float dx = xv.x - r.x, dy = xv.y - r.y, dz = xv.z - r.z, dwv = xv.w - r.w;
  float s = dx * dx + dy * dy + dz * dz + dwv * dwv;
  #pragma unroll
  for (int off = 32; off > 0; off >>= 1) s += __shfl_down(s, off);
  if ((threadIdx.x & 63) == 0) lds[threadIdx.x >> 6] = s;
  __syncthreads();
  if (threadIdx.x == 0) partials[blockIdx.x] = lds[0] + lds[1] + lds[2] + lds[3];
}

// ------------------------------------------------- ema_w_new + embed_new ----
__global__ __launch_bounds__(256)
void emb_kernel(const float* __restrict__ ema_w, const float* __restrict__ dw,
                const float* __restrict__ cs,
                float* __restrict__ out_ema_w, float* __restrict__ out_embed) {
  const int g = blockIdx.x * 256 + threadIdx.x;
  const int k = g >> 8;
  const float e = ema_w[g] * 0.99f + 0.01f * dw[g];
  out_ema_w[g] = e;
  out_embed[g] = e / cs[k];
}

// ---------------------------------------------------------- loss finalize ----
__global__ __launch_bounds__(256)
void loss_fin_kernel(const float* __restrict__ partials, float* __restrict__ out_loss) {
  __shared__ float lds[4];
  float s = 0.0f;
  for (int i = threadIdx.x; i < 4096; i += 256) s += partials[i];
  #pragma unroll
  for (int off = 32; off > 0; off >>= 1) s += __shfl_down(s, off);
  if ((threadIdx.x & 63) == 0) lds[threadIdx.x >> 6] = s;
  __syncthreads();
  if (threadIdx.x == 0) {
    const float total = lds[0] + lds[1] + lds[2] + lds[3];
    out_loss[0] = 0.25f * (total / 4194304.0f);
  }
}

// ------------------------------------------------------------------ launch ----
extern "C" void kernel_launch(void* const* d_in, const int* in_sizes, int n_in,
                              void* d_out, int out_size, void* d_ws, size_t ws_size,
                              hipStream_t stream) {
  const float* x       = (const float*)d_in[0];
  const float* embed_w = (const float*)d_in[1];
  const float* ema_cs  = (const float*)d_in[2];
  const float* ema_w   = (const float*)d_in[3];

  float* out        = (float*)d_out;
  float* out_q      = out;                 // 4194304
  float* out_loss   = out + 4194304;       // 1
  float* out_embed  = out + 4194305;       // 262144
  float* out_cs     = out + 4456449;       // 1024
  float* out_ema_w  = out + 4457473;       // 262144

  char* ws = (char*)d_ws;
  u64*   pairs    = (u64*)  (ws + 0);                          // 1048576 B
  int*   idx      = (int*)  (ws + 1048576);                    // 65536 B
  float* counts   = (float*)(ws + 1114112);                    // 4096 B
  float* dw       = (float*)(ws + 1118208);                    // 1048576 B (also wpk)
  float* cs_ws    = (float*)(ws + 2166784);                    // 4096 B
  float* wnorm    = (float*)(ws + 2170880);                    // 4096 B
  float* partials = (float*)(ws + 2174976);                    // 16384 B
  int*   flags    = (int*)  (ws + 2191360);                    // 32768 B
  int*   counter  = (int*)  (ws + 2224128);                    // 4 B
  // Bucket structures alias the pairs region (free after merge_kernel):
  int*   bucket   = (int*)  (ws + 0);                          // 65536 B
  int*   starts   = (int*)  (ws + 65536);                      // 4096 B
  int*   cursor   = (int*)  (ws + 69632);                      // 4096 B

  // xpk aliases out_q (overwritten by quant later); wpk aliases dw
  // (dw written by dw_bucket only after dist has consumed wpk).
  uint32_t* xpk = (uint32_t*)out_q;
  uint32_t* wpk = (uint32_t*)dw;

  hipMemsetAsync(counts, 0, 4096, stream);
  hipMemsetAsync(counter, 0, 4, stream);

  pack_kernel<<<4352, 256, 0, stream>>>((const float4*)x, (const float4*)embed_w,
                                        (uint4*)xpk, (uint4*)wpk);
  wnorm_np_kernel<<<KC / 256, 256, 0, stream>>>(embed_w, wnorm);
  dist_mfma_kernel<<<(NROW / MT) * KSPLIT, 256, 0, stream>>>(xpk, wpk, wnorm, pairs);
  merge_kernel<<<NROW / 256, 256, 0, stream>>>(pairs, idx, counts, flags, counter);
  recheck_np_kernel<<<FCAP / RPB, 256, 0, stream>>>(x, embed_w, wnorm, flags, counter,
                                                    idx, counts);
  prefix_kernel<<<1, 1024, 0, stream>>>(counts, starts, cursor);
  scatter_kernel<<<NROW / 256, 256, 0, stream>>>(idx, cursor, bucket);
  dw_bucket_kernel<<<KC, 256, 0, stream>>>((const float4*)x, bucket, starts, counts,
                                           (float4*)dw);
  cs_kernel<<<1, 1024, 0, stream>>>(ema_cs, counts, out_cs, cs_ws);
  quant_loss_kernel<<<NROW * 64 / 256, 256, 0, stream>>>(
      (const float4*)x, (const float4*)embed_w, idx, (float4*)out_q, partials);
  emb_kernel<<<KC * DIM / 256, 256, 0, stream>>>(ema_w, dw, cs_ws, out_ema_w, out_embed);
  loss_fin_kernel<<<1, 256, 0, stream>>>(partials, out_loss);
}

// Round 7
// 205.346 us; speedup vs baseline: 3.1132x; 1.1608x over previous
//
#include <hip/hip_runtime.h>
#include <cstdint>
#include <cstddef>

// Problem constants (B=16, T=1024, D=256, K=1024)
namespace {
constexpr int NROW = 16384;   // B*T
constexpr int KC   = 1024;    // codes
constexpr int DIM  = 256;
constexpr int MT   = 128;     // rows per block (argmin GEMM)
constexpr int KSPLIT = 4;     // codes partitioned across blocks
constexpr int KPB  = KC / KSPLIT;   // 256 codes per block
constexpr int FCAP = 8192;    // flagged-row capacity (expect ~450)
constexpr int RPB  = 4;       // flagged rows per recheck block
}

typedef __attribute__((ext_vector_type(8))) short bf16x8;
typedef __attribute__((ext_vector_type(4))) float f32x4;
typedef unsigned long long u64;
typedef uint32_t u32;

// Monotone float -> uint key (ascending), for packed argmin with index tie-break.
__device__ __forceinline__ unsigned fkey(float s) {
  unsigned u = __float_as_uint(s);
  return ((int)u >= 0) ? (u ^ 0x80000000u) : ~u;
}
__device__ __forceinline__ float unfkey(unsigned u) {
  return __uint_as_float((u & 0x80000000u) ? (u ^ 0x80000000u) : ~u);
}

// Split fp32 a into RNE-bf16 hi + RNE-bf16 of exact residual (low 16 bits each).
__device__ __forceinline__ void split2(float a, u32& h, u32& l) {
  const u32 u  = __float_as_uint(a);
  const u32 rh = (u + 0x7fffu + ((u >> 16) & 1u)) >> 16;
  const float ah = __uint_as_float(rh << 16);
  const float al = a - ah;                      // exact (Sterbenz)
  const u32 v  = __float_as_uint(al);
  const u32 rl = (v + 0x7fffu + ((v >> 16) & 1u)) >> 16;
  h = rh & 0xffffu; l = rl & 0xffffu;
}

// numpy pairwise sum of squares of 256 floats, bit-exact emulation.
__device__ __forceinline__ float np_sumsq_256(const float* __restrict__ p) {
  float half[2];
  #pragma unroll
  for (int h = 0; h < 2; h++) {
    const float* q = p + h * 128;
    float r[8];
    #pragma unroll
    for (int j = 0; j < 8; j++) r[j] = __fmul_rn(q[j], q[j]);
    #pragma unroll 1
    for (int i = 8; i < 128; i += 8)
      #pragma unroll
      for (int j = 0; j < 8; j++)
        r[j] = __fadd_rn(r[j], __fmul_rn(q[i + j], q[i + j]));
    half[h] = __fadd_rn(__fadd_rn(__fadd_rn(r[0], r[1]), __fadd_rn(r[2], r[3])),
                        __fadd_rn(__fadd_rn(r[4], r[5]), __fadd_rn(r[6], r[7])));
  }
  return __fadd_rn(half[0], half[1]);
}

// ------------------------------------------------- pack planes + wnorm ----
// Blocks [0,2176): split-pack x and w into hi/lo bf16 planes (8 elems/thread).
// Blocks [2176,2180): numpy-exact ||w_k||^2.
__global__ __launch_bounds__(256)
void pack_wnorm_kernel(const float4* __restrict__ x4, const float4* __restrict__ w4,
                       const float* __restrict__ w,
                       uint4* __restrict__ xh4, uint4* __restrict__ xl4,
                       uint4* __restrict__ wh4, uint4* __restrict__ wl4,
                       float* __restrict__ wnorm) {
  if (blockIdx.x >= 2176) {
    const int k = (blockIdx.x - 2176) * 256 + threadIdx.x;
    wnorm[k] = np_sumsq_256(&w[k * DIM]);
    return;
  }
  const int g = blockIdx.x * 256 + threadIdx.x;
  const float4* src; uint4* dh; uint4* dl; int gg;
  if (g < 524288) { gg = g;          src = x4; dh = xh4; dl = xl4; }
  else            { gg = g - 524288; src = w4; dh = wh4; dl = wl4; }
  const float4 a = src[gg * 2], b = src[gg * 2 + 1];
  u32 h[8], l[8];
  split2(a.x, h[0], l[0]); split2(a.y, h[1], l[1]);
  split2(a.z, h[2], l[2]); split2(a.w, h[3], l[3]);
  split2(b.x, h[4], l[4]); split2(b.y, h[5], l[5]);
  split2(b.z, h[6], l[6]); split2(b.w, h[7], l[7]);
  uint4 H, L;
  H.x = h[0] | (h[1] << 16); H.y = h[2] | (h[3] << 16);
  H.z = h[4] | (h[5] << 16); H.w = h[6] | (h[7] << 16);
  L.x = l[0] | (l[1] << 16); L.y = l[2] | (l[3] << 16);
  L.z = l[4] | (l[5] << 16); L.w = l[6] | (l[7] << 16);
  dh[gg] = H; dl[gg] = L;
}

// ------------------------------------------- split-bf16 MFMA dist + top-2 ----
// Planes layout: LDS per kc: AH[128r x 64B] AL BH[256c x 64B] BL, row-major.
// global_load_lds dest = chunkBase + lane*16 == (lane>>2)*64 + (lane&3)*16. :)
// Fragment reads are b128 direct (no unpack); 16-lane phases read 256 B
// contiguous -> conflict-free by construction.
__global__ __launch_bounds__(256, 2)
void dist_mfma_kernel(const ushort* __restrict__ xh, const ushort* __restrict__ xl,
                      const ushort* __restrict__ wh, const ushort* __restrict__ wl,
                      const float* __restrict__ wnorm,
                      u64* __restrict__ pairs) {
  __shared__ __align__(16) u32 lds[12288];   // 48 KB

  const int tid  = threadIdx.x;
  const int lane = tid & 63;
  const int wv   = tid >> 6;
  const int quad = lane >> 4;
  const int idx16 = lane & 15;
  const int rowBase = (blockIdx.x >> 2) * MT;
  const int sp      = blockIdx.x & 3;
  const int kbase   = sp * KPB;

  // 48 staging chunks of 1 KB (16 rows x 64 B); wave wv handles 12.
  const int subrow = lane >> 2, grp = lane & 3;
  const ushort* gptr[12];
  u32 ldst[12];
  #pragma unroll
  for (int j = 0; j < 12; j++) {
    const int c = wv * 12 + j;
    const ushort* plane; int r0; u32 dstB;
    if (c < 8)       { plane = xh + rowBase * DIM; r0 = c * 16;        dstB = c * 1024; }
    else if (c < 16) { plane = xl + rowBase * DIM; r0 = (c - 8) * 16;  dstB = 8192 + (c - 8) * 1024; }
    else if (c < 32) { plane = wh + kbase * DIM;   r0 = (c - 16) * 16; dstB = 16384 + (c - 16) * 1024; }
    else             { plane = wl + kbase * DIM;   r0 = (c - 32) * 16; dstB = 32768 + (c - 32) * 1024; }
    gptr[j] = plane + (r0 + subrow) * DIM + grp * 8;
    ldst[j] = dstB >> 2;
  }

  f32x4 acc[2][16];
  #pragma unroll
  for (int rt = 0; rt < 2; rt++)
    #pragma unroll
    for (int ct = 0; ct < 16; ct++) acc[rt][ct] = (f32x4){0.f, 0.f, 0.f, 0.f};

  #pragma unroll 1
  for (int kc = 0; kc < DIM / 32; kc++) {
    __syncthreads();   // previous readers done
    #pragma unroll
    for (int j = 0; j < 12; j++) {
      __builtin_amdgcn_global_load_lds(
          (const __attribute__((address_space(1))) u32*)(gptr[j]),
          (__attribute__((address_space(3))) u32*)&lds[ldst[j]], 16, 0, 0);
      gptr[j] += 32;   // next 32 K-elems
    }
    __syncthreads();   // drains vmcnt; LDS visible

    bf16x8 Ah[2], Al[2];
    #pragma unroll
    for (int rt = 0; rt < 2; rt++) {
      const int ar = wv * 32 + rt * 16 + idx16;
      Ah[rt] = *(const bf16x8*)((const char*)lds + ar * 64 + quad * 16);
      Al[rt] = *(const bf16x8*)((const char*)lds + 8192 + ar * 64 + quad * 16);
    }
    #pragma unroll
    for (int ct = 0; ct < 16; ct++) {
      const int br = ct * 16 + idx16;
      const bf16x8 Bh = *(const bf16x8*)((const char*)lds + 16384 + br * 64 + quad * 16);
      const bf16x8 Bl = *(const bf16x8*)((const char*)lds + 32768 + br * 64 + quad * 16);
      #pragma unroll
      for (int rt = 0; rt < 2; rt++) {
        acc[rt][ct] = __builtin_amdgcn_mfma_f32_16x16x32_bf16(Al[rt], Bh, acc[rt][ct], 0, 0, 0);
        acc[rt][ct] = __builtin_amdgcn_mfma_f32_16x16x32_bf16(Ah[rt], Bl, acc[rt][ct], 0, 0, 0);
        acc[rt][ct] = __builtin_amdgcn_mfma_f32_16x16x32_bf16(Ah[rt], Bh, acc[rt][ct], 0, 0, 0);
      }
    }
  }

  // Epilogue: score = wnorm - 2*dot; per-lane top-2, then 4-stage butterfly.
  u64 b0[2][4], b1[2][4];
  #pragma unroll
  for (int rt = 0; rt < 2; rt++)
    #pragma unroll
    for (int reg = 0; reg < 4; reg++) { b0[rt][reg] = ~0ULL; b1[rt][reg] = ~0ULL; }

  #pragma unroll
  for (int ct = 0; ct < 16; ct++) {
    const int col = kbase + ct * 16 + idx16;
    const float wn = wnorm[col];
    #pragma unroll
    for (int rt = 0; rt < 2; rt++) {
      #pragma unroll
      for (int reg = 0; reg < 4; reg++) {
        const float s = fmaf(-2.0f, acc[rt][ct][reg], wn);
        const u64 p = ((u64)fkey(s) << 32) | (unsigned)col;
        if (p < b1[rt][reg]) {
          if (p < b0[rt][reg]) { b1[rt][reg] = b0[rt][reg]; b0[rt][reg] = p; }
          else                 { b1[rt][reg] = p; }
        }
      }
    }
  }

  #pragma unroll
  for (int m = 1; m <= 8; m <<= 1) {
    #pragma unroll
    for (int rt = 0; rt < 2; rt++) {
      #pragma unroll
      for (int reg = 0; reg < 4; reg++) {
        const u64 o0 = __shfl_xor(b0[rt][reg], m);
        const u64 o1 = __shfl_xor(b1[rt][reg], m);
        if (o0 < b0[rt][reg]) {
          b1[rt][reg] = (b0[rt][reg] < o1) ? b0[rt][reg] : o1;
          b0[rt][reg] = o0;
        } else {
          b1[rt][reg] = (b1[rt][reg] < o0) ? b1[rt][reg] : o0;
        }
      }
    }
  }

  if (idx16 == 0) {
    #pragma unroll
    for (int rt = 0; rt < 2; rt++) {
      #pragma unroll
      for (int reg = 0; reg < 4; reg++) {
        const int row = rowBase + wv * 32 + rt * 16 + quad * 4 + reg;
        pairs[row * 8 + sp * 2 + 0] = b0[rt][reg];
        pairs[row * 8 + sp * 2 + 1] = b1[rt][reg];
      }
    }
  }
}

// ------------------------------------- merge splits + flag + counts ----
__global__ __launch_bounds__(256)
void merge_kernel(const u64* __restrict__ pairs,
                  int* __restrict__ idx, float* __restrict__ counts,
                  int* __restrict__ flags, int* __restrict__ counter) {
  const int row = blockIdx.x * 256 + threadIdx.x;
  const u64* p = &pairs[row * 8];
  u64 B0 = p[0], B1 = p[1];
  #pragma unroll
  for (int s = 1; s < KSPLIT; s++) {
    const u64 c0 = p[s * 2], c1 = p[s * 2 + 1];
    if (c0 < B0) { B1 = (B0 < c1) ? B0 : c1; B0 = c0; }
    else         { B1 = (B1 < c0) ? B1 : c0; }
  }
  const int k = (int)(B0 & 0xffffffffULL);
  idx[row] = k;
  atomicAdd(&counts[k], 1.0f);
  const float s0 = unfkey((unsigned)(B0 >> 32));
  const float s1 = unfkey((unsigned)(B1 >> 32));
  if (s1 - s0 < 2e-4f) {
    const int pos = atomicAdd(counter, 1);
    if (pos < FCAP) flags[pos] = row;
  }
}

// --------------------- np-fp32-emulating recheck; adjusts counts on flips ----
__global__ __launch_bounds__(256)
void recheck_np_kernel(const float* __restrict__ x, const float* __restrict__ w,
                       const float* __restrict__ wnorm,
                       const int* __restrict__ flags, const int* __restrict__ counter,
                       int* __restrict__ idx, float* __restrict__ counts) {
  __shared__ float xs[RPB][DIM];
  __shared__ float x2sh[RPB];
  __shared__ u64 red[RPB][256];

  const int cnt  = min(*counter, FCAP);
  const int base = blockIdx.x * RPB;
  if (base >= cnt) return;
  const int nr = min(RPB, cnt - base);

  #pragma unroll
  for (int r = 0; r < RPB; r++)
    xs[r][threadIdx.x] = (r < nr) ? x[flags[base + r] * DIM + threadIdx.x] : 0.0f;
  __syncthreads();
  if (threadIdx.x < RPB) x2sh[threadIdx.x] = np_sumsq_256(xs[threadIdx.x]);
  __syncthreads();
  double x2d[RPB];
  #pragma unroll
  for (int r = 0; r < RPB; r++) x2d[r] = (double)x2sh[r];

  u64 best[RPB];
  #pragma unroll
  for (int r = 0; r < RPB; r++) best[r] = ~0ULL;

  #pragma unroll 1
  for (int g = 0; g < 4; g++) {
    const int k = threadIdx.x * 4 + g;
    const float* wr = &w[k * DIM];
    const double w2 = (double)wnorm[k];
    double dot[RPB];
    #pragma unroll
    for (int r = 0; r < RPB; r++) dot[r] = 0.0;
    #pragma unroll 1
    for (int d = 0; d < DIM; d += 4) {
      const float4 wv = *(const float4*)&wr[d];
      #pragma unroll
      for (int r = 0; r < RPB; r++) {
        dot[r] = fma((double)xs[r][d],     (double)wv.x, dot[r]);
        dot[r] = fma((double)xs[r][d + 1], (double)wv.y, dot[r]);
        dot[r] = fma((double)xs[r][d + 2], (double)wv.z, dot[r]);
        dot[r] = fma((double)xs[r][d + 3], (double)wv.w, dot[r]);
      }
    }
    #pragma unroll
    for (int r = 0; r < RPB; r++) {
      const float mmf = (float)dot[r];
      const float S1  = (float)(x2d[r] + w2);
      const float D   = (float)((double)S1 - 2.0 * (double)mmf);
      const u64 key = ((u64)fkey(D) << 32) | (unsigned)k;
      if (key < best[r]) best[r] = key;
    }
  }

  #pragma unroll
  for (int r = 0; r < RPB; r++) red[r][threadIdx.x] = best[r];
  __syncthreads();
  #pragma unroll
  for (int off = 128; off > 0; off >>= 1) {
    if ((int)threadIdx.x < off) {
      #pragma unroll
      for (int r = 0; r < RPB; r++) {
        const u64 o = red[r][threadIdx.x + off];
        if (o < red[r][threadIdx.x]) red[r][threadIdx.x] = o;
      }
    }
    __syncthreads();
  }
  if ((int)threadIdx.x < nr) {
    const int row  = flags[base + threadIdx.x];
    const int newk = (int)(red[threadIdx.x][0] & 0xffffffffULL);
    const int oldk = idx[row];
    if (newk != oldk) {
      idx[row] = newk;
      atomicAdd(&counts[newk],  1.0f);
      atomicAdd(&counts[oldk], -1.0f);
    }
  }
}

// ------------------------------- fused prefix scan (starts/cursor) + cs ----
__global__ __launch_bounds__(1024)
void prefix_cs_kernel(const float* __restrict__ ema_cs, const float* __restrict__ counts,
                      int* __restrict__ starts, int* __restrict__ cursor,
                      float* __restrict__ out_cs, float* __restrict__ cs_ws) {
  __shared__ int sc[1024];
  __shared__ float lds[17];
  const int t = threadIdx.x;
  const int ci = (int)counts[t];
  sc[t] = ci;
  const float c = ema_cs[t] * 0.99f + 0.01f * counts[t];
  float v = c;
  #pragma unroll
  for (int off = 32; off > 0; off >>= 1) v += __shfl_down(v, off);
  if ((t & 63) == 0) lds[t >> 6] = v;
  __syncthreads();
  if (t == 0) {
    float n = 0.0f;
    for (int i = 0; i < 16; i++) n += lds[i];
    lds[16] = n;
  }
  __syncthreads();
  const float n = lds[16];
  const float csv = (c + 1e-5f) / (n + 1024.0f * 1e-5f) * n;
  out_cs[t] = csv;
  cs_ws[t]  = csv;
  // prefix scan
  #pragma unroll
  for (int off = 1; off < 1024; off <<= 1) {
    const int add = (t >= off) ? sc[t - off] : 0;
    __syncthreads();
    sc[t] += add;
    __syncthreads();
  }
  const int excl = sc[t] - ci;
  starts[t] = excl;
  cursor[t] = excl;
}

// ------------------------------------------------------ bucket scatter ----
__global__ __launch_bounds__(256)
void scatter_kernel(const int* __restrict__ idx, int* __restrict__ cursor,
                    int* __restrict__ bucket) {
  const int row = blockIdx.x * 256 + threadIdx.x;
  const int k = idx[row];
  const int pos = atomicAdd(&cursor[k], 1);
  bucket[pos] = row;
}

// ----------------------------------- per-cluster dw reduction (no atomics) ----
__global__ __launch_bounds__(256)
void dw_bucket_kernel(const float4* __restrict__ x4, const int* __restrict__ bucket,
                      const int* __restrict__ starts, const float* __restrict__ counts,
                      float4* __restrict__ dw4) {
  __shared__ float4 red[4][64];
  const int k   = blockIdx.x;
  const int d4  = threadIdx.x & 63;
  const int rg  = threadIdx.x >> 6;
  const int s   = starts[k];
  const int e   = s + (int)counts[k];
  float4 acc = {0.f, 0.f, 0.f, 0.f};
  for (int i = s + rg; i < e; i += 4) {
    const float4 v = x4[bucket[i] * 64 + d4];
    acc.x += v.x; acc.y += v.y; acc.z += v.z; acc.w += v.w;
  }
  red[rg][d4] = acc;
  __syncthreads();
  if (rg == 0) {
    const float4 a1 = red[1][d4], a2 = red[2][d4], a3 = red[3][d4];
    acc.x += a1.x + a2.x + a3.x;
    acc.y += a1.y + a2.y + a3.y;
    acc.z += a1.z + a2.z + a3.z;
    acc.w += a1.w + a2.w + a3.w;
    dw4[k * 64 + d4] = acc;
  }
}

// ------------------------------------------- quantize + loss (no atomics) ----
__global__ __launch_bounds__(256)
void quant_loss_kernel(const float4* __restrict__ x4,
                       const float4* __restrict__ w4,
                       const int* __restrict__ idx,
                       float4* __restrict__ outq,
                       float* __restrict__ partials) {
  __shared__ float lds[4];
  const int g  = blockIdx.x * 256 + threadIdx.x;
  const int n  = g >> 6;
  const int d4 = g & 63;
  const float4 xv = x4[g];
  const int   k  = idx[n];
  const float4 qv = w4[k * 64 + d4];
  float4 r;
  r.x = xv.x + (qv.x - xv.x);
  r.y = xv.y + (qv.y - xv.y);
  r.z = xv.z + (qv.z - xv.z);
  r.w = xv.w + (qv.w - xv.w);
  outq[g] = r;

  const float dx = xv.x - r.x, dy = xv.y - r.y, dz = xv.z - r.z, dwv = xv.w - r.w;
  float s = dx * dx + dy * dy + dz * dz + dwv * dwv;
  #pragma unroll
  for (int off = 32; off > 0; off >>= 1) s += __shfl_down(s, off);
  if ((threadIdx.x & 63) == 0) lds[threadIdx.x >> 6] = s;
  __syncthreads();
  if (threadIdx.x == 0) partials[blockIdx.x] = lds[0] + lds[1] + lds[2] + lds[3];
}

// --------------------------------- fused ema_w/embed (+ loss finalize) ----
__global__ __launch_bounds__(256)
void emb_loss_kernel(const float* __restrict__ ema_w, const float* __restrict__ dw,
                     const float* __restrict__ cs, const float* __restrict__ partials,
                     float* __restrict__ out_ema_w, float* __restrict__ out_embed,
                     float* __restrict__ out_loss) {
  if (blockIdx.x == 1024) {
    __shared__ float lds[4];
    float s = 0.0f;
    for (int i = threadIdx.x; i < 4096; i += 256) s += partials[i];
    #pragma unroll
    for (int off = 32; off > 0; off >>= 1) s += __shfl_down(s, off);
    if ((threadIdx.x & 63) == 0) lds[threadIdx.x >> 6] = s;
    __syncthreads();
    if (threadIdx.x == 0) {
      const float total = lds[0] + lds[1] + lds[2] + lds[3];
      out_loss[0] = 0.25f * (total / 4194304.0f);
    }
    return;
  }
  const int g = blockIdx.x * 256 + threadIdx.x;
  const int k = g >> 8;
  const float e = ema_w[g] * 0.99f + 0.01f * dw[g];
  out_ema_w[g] = e;
  out_embed[g] = e / cs[k];
}

// ------------------------------------------------------------------ launch ----
extern "C" void kernel_launch(void* const* d_in, const int* in_sizes, int n_in,
                              void* d_out, int out_size, void* d_ws, size_t ws_size,
                              hipStream_t stream) {
  const float* x       = (const float*)d_in[0];
  const float* embed_w = (const float*)d_in[1];
  const float* ema_cs  = (const float*)d_in[2];
  const float* ema_w   = (const float*)d_in[3];

  float* out        = (float*)d_out;
  float* out_q      = out;                 // 4194304
  float* out_loss   = out + 4194304;       // 1
  float* out_embed  = out + 4194305;       // 262144
  float* out_cs     = out + 4456449;       // 1024
  float* out_ema_w  = out + 4457473;       // 262144

  char* ws = (char*)d_ws;
  u64*   pairs    = (u64*)  (ws + 0);           // 1 MB
  int*   idx      = (int*)  (ws + 1048576);     // 64 KB
  float* counts   = (float*)(ws + 1114112);     // 4 KB
  int*   counter  = (int*)  (ws + 1118208);     // 4 B (adjacent to counts)
  int*   flags    = (int*)  (ws + 1118336);     // 32 KB
  float* wnorm    = (float*)(ws + 1151104);     // 4 KB
  float* cs_ws    = (float*)(ws + 1155200);     // 4 KB
  float* partials = (float*)(ws + 1159296);     // 16 KB
  int*   starts   = (int*)  (ws + 1175680);     // 4 KB
  int*   cursor   = (int*)  (ws + 1179776);     // 4 KB
  float* dw       = (float*)(ws + 1183872);     // 1 MB (wh/wl planes before dw)
  // bucket aliases pairs (free after merge)
  int*   bucket   = (int*)  (ws + 0);           // 64 KB

  // x planes alias out_q (16 MB exactly); w planes alias dw (1 MB).
  ushort* xh = (ushort*)out_q;                  // 8 MB
  ushort* xl = (ushort*)out_q + 4194304;        // 8 MB
  ushort* wh = (ushort*)dw;                     // 512 KB
  ushort* wl = (ushort*)dw + 262144;            // 512 KB

  hipMemsetAsync(counts, 0, 4100, stream);      // counts + counter

  pack_wnorm_kernel<<<2180, 256, 0, stream>>>(
      (const float4*)x, (const float4*)embed_w, embed_w,
      (uint4*)xh, (uint4*)xl, (uint4*)wh, (uint4*)wl, wnorm);
  dist_mfma_kernel<<<(NROW / MT) * KSPLIT, 256, 0, stream>>>(xh, xl, wh, wl, wnorm, pairs);
  merge_kernel<<<NROW / 256, 256, 0, stream>>>(pairs, idx, counts, flags, counter);
  recheck_np_kernel<<<FCAP / RPB, 256, 0, stream>>>(x, embed_w, wnorm, flags, counter,
                                                    idx, counts);
  prefix_cs_kernel<<<1, 1024, 0, stream>>>(ema_cs, counts, starts, cursor, out_cs, cs_ws);
  scatter_kernel<<<NROW / 256, 256, 0, stream>>>(idx, cursor, bucket);
  dw_bucket_kernel<<<KC, 256, 0, stream>>>((const float4*)x, bucket, starts, counts,
                                           (float4*)dw);
  quant_loss_kernel<<<NROW * 64 / 256, 256, 0, stream>>>(
      (const float4*)x, (const float4*)embed_w, idx, (float4*)out_q, partials);
  emb_loss_kernel<<<KC * DIM / 256 + 1, 256, 0, stream>>>(
      ema_w, dw, cs_ws, partials, out_ema_w, out_embed, out_loss);
}

// Round 11
// 204.509 us; speedup vs baseline: 3.1260x; 1.0041x over previous
//
#include <hip/hip_runtime.h>
#include <cstdint>
#include <cstddef>

// Problem constants (B=16, T=1024, D=256, K=1024)
namespace {
constexpr int NROW = 16384;   // B*T
constexpr int KC   = 1024;    // codes
constexpr int DIM  = 256;
constexpr int MT   = 128;     // rows per block (argmin GEMM)
constexpr int KSPLIT = 8;     // codes partitioned across blocks
constexpr int KPB  = KC / KSPLIT;   // 128 codes per block
constexpr int FCAP = 8192;    // flagged-row capacity (expect ~450)
constexpr int RPB  = 4;       // flagged rows per recheck block
}

typedef __attribute__((ext_vector_type(8))) short bf16x8;
typedef __attribute__((ext_vector_type(4))) float f32x4;
typedef unsigned long long u64;
typedef uint32_t u32;

// Monotone float -> uint key (ascending), for packed argmin with index tie-break.
__device__ __forceinline__ unsigned fkey(float s) {
  unsigned u = __float_as_uint(s);
  return ((int)u >= 0) ? (u ^ 0x80000000u) : ~u;
}
__device__ __forceinline__ float unfkey(unsigned u) {
  return __uint_as_float((u & 0x80000000u) ? (u ^ 0x80000000u) : ~u);
}

// Split fp32 a into RNE-bf16 hi + RNE-bf16 of exact residual (low 16 bits each).
__device__ __forceinline__ void split2(float a, u32& h, u32& l) {
  const u32 u  = __float_as_uint(a);
  const u32 rh = (u + 0x7fffu + ((u >> 16) & 1u)) >> 16;
  const float ah = __uint_as_float(rh << 16);
  const float al = a - ah;                      // exact (Sterbenz)
  const u32 v  = __float_as_uint(al);
  const u32 rl = (v + 0x7fffu + ((v >> 16) & 1u)) >> 16;
  h = rh & 0xffffu; l = rl & 0xffffu;
}

// numpy pairwise sum of squares of 256 floats, bit-exact emulation.
__device__ __forceinline__ float np_sumsq_256(const float* __restrict__ p) {
  float half[2];
  #pragma unroll
  for (int h = 0; h < 2; h++) {
    const float* q = p + h * 128;
    float r[8];
    #pragma unroll
    for (int j = 0; j < 8; j++) r[j] = __fmul_rn(q[j], q[j]);
    #pragma unroll 1
    for (int i = 8; i < 128; i += 8)
      #pragma unroll
      for (int j = 0; j < 8; j++)
        r[j] = __fadd_rn(r[j], __fmul_rn(q[i + j], q[i + j]));
    half[h] = __fadd_rn(__fadd_rn(__fadd_rn(r[0], r[1]), __fadd_rn(r[2], r[3])),
                        __fadd_rn(__fadd_rn(r[4], r[5]), __fadd_rn(r[6], r[7])));
  }
  return __fadd_rn(half[0], half[1]);
}

// ------------------------------------------------- pack planes + wnorm ----
__global__ __launch_bounds__(256)
void pack_wnorm_kernel(const float4* __restrict__ x4, const float4* __restrict__ w4,
                       const float* __restrict__ w,
                       uint4* __restrict__ xh4, uint4* __restrict__ xl4,
                       uint4* __restrict__ wh4, uint4* __restrict__ wl4,
                       float* __restrict__ wnorm) {
  if (blockIdx.x >= 2176) {
    const int k = (blockIdx.x - 2176) * 256 + threadIdx.x;
    wnorm[k] = np_sumsq_256(&w[k * DIM]);
    return;
  }
  const int g = blockIdx.x * 256 + threadIdx.x;
  const float4* src; uint4* dh; uint4* dl; int gg;
  if (g < 524288) { gg = g;          src = x4; dh = xh4; dl = xl4; }
  else            { gg = g - 524288; src = w4; dh = wh4; dl = wl4; }
  const float4 a = src[gg * 2], b = src[gg * 2 + 1];
  u32 h[8], l[8];
  split2(a.x, h[0], l[0]); split2(a.y, h[1], l[1]);
  split2(a.z, h[2], l[2]); split2(a.w, h[3], l[3]);
  split2(b.x, h[4], l[4]); split2(b.y, h[5], l[5]);
  split2(b.z, h[6], l[6]); split2(b.w, h[7], l[7]);
  uint4 H, L;
  H.x = h[0] | (h[1] << 16); H.y = h[2] | (h[3] << 16);
  H.z = h[4] | (h[5] << 16); H.w = h[6] | (h[7] << 16);
  L.x = l[0] | (l[1] << 16); L.y = l[2] | (l[3] << 16);
  L.z = l[4] | (l[5] << 16); L.w = l[6] | (l[7] << 16);
  dh[gg] = H; dl[gg] = L;
}

// ------------------------------------------- split-bf16 MFMA dist + top-2 ----
// KSPLIT=8: block = 128 rows x 128 codes, 32 KB LDS. Staging is the R7-verified
// lane-contiguous global_load_lds pattern. XCD swizzle: the 8 ksplit siblings
// of a row-block share bid%8 -> same XCD L2.
__global__ __launch_bounds__(256, 3)
void dist_mfma_kernel(const ushort* __restrict__ xh, const ushort* __restrict__ xl,
                      const ushort* __restrict__ wh, const ushort* __restrict__ wl,
                      const float* __restrict__ wnorm,
                      u64* __restrict__ pairs) {
  __shared__ __align__(16) u32 lds[8192];   // 32 KB: AH 8K | AL 8K | BH 8K | BL 8K

  const int tid  = threadIdx.x;
  const int lane = tid & 63;
  const int wv   = tid >> 6;
  const int quad = lane >> 4;
  const int idx16 = lane & 15;
  const int bid  = blockIdx.x;
  const int rowBase = (((bid >> 6) << 3) | (bid & 7)) * MT;
  const int sp      = (bid >> 3) & 7;
  const int kbase   = sp * KPB;

  // 32 staging chunks of 1 KB (16 rows x 64 B); wave wv handles 8.
  const int subrow = lane >> 2, grp = lane & 3;
  const ushort* gptr[8];
  u32 ldst[8];
  #pragma unroll
  for (int j = 0; j < 8; j++) {
    const int c = wv * 8 + j;
    const ushort* plane; int r0; u32 dstB;
    if (c < 8)       { plane = xh + rowBase * DIM; r0 = c * 16;        dstB = c * 1024; }
    else if (c < 16) { plane = xl + rowBase * DIM; r0 = (c - 8) * 16;  dstB = 8192 + (c - 8) * 1024; }
    else if (c < 24) { plane = wh + kbase * DIM;   r0 = (c - 16) * 16; dstB = 16384 + (c - 16) * 1024; }
    else             { plane = wl + kbase * DIM;   r0 = (c - 24) * 16; dstB = 24576 + (c - 24) * 1024; }
    gptr[j] = plane + (r0 + subrow) * DIM + grp * 8;
    ldst[j] = dstB >> 2;
  }

  f32x4 acc[2][8];
  #pragma unroll
  for (int rt = 0; rt < 2; rt++)
    #pragma unroll
    for (int ct = 0; ct < 8; ct++) acc[rt][ct] = (f32x4){0.f, 0.f, 0.f, 0.f};

  #pragma unroll 1
  for (int kc = 0; kc < DIM / 32; kc++) {
    __syncthreads();   // previous readers done
    #pragma unroll
    for (int j = 0; j < 8; j++) {
      __builtin_amdgcn_global_load_lds(
          (const __attribute__((address_space(1))) u32*)(gptr[j]),
          (__attribute__((address_space(3))) u32*)&lds[ldst[j]], 16, 0, 0);
      gptr[j] += 32;   // next 32 K-elems
    }
    __syncthreads();   // drains vmcnt; LDS visible

    bf16x8 Ah[2], Al[2];
    #pragma unroll
    for (int rt = 0; rt < 2; rt++) {
      const int ar = wv * 32 + rt * 16 + idx16;
      Ah[rt] = *(const bf16x8*)((const char*)lds + ar * 64 + quad * 16);
      Al[rt] = *(const bf16x8*)((const char*)lds + 8192 + ar * 64 + quad * 16);
    }
    #pragma unroll
    for (int ct = 0; ct < 8; ct++) {
      const int br = ct * 16 + idx16;
      const bf16x8 Bh = *(const bf16x8*)((const char*)lds + 16384 + br * 64 + quad * 16);
      const bf16x8 Bl = *(const bf16x8*)((const char*)lds + 24576 + br * 64 + quad * 16);
      #pragma unroll
      for (int rt = 0; rt < 2; rt++) {
        acc[rt][ct] = __builtin_amdgcn_mfma_f32_16x16x32_bf16(Al[rt], Bh, acc[rt][ct], 0, 0, 0);
        acc[rt][ct] = __builtin_amdgcn_mfma_f32_16x16x32_bf16(Ah[rt], Bl, acc[rt][ct], 0, 0, 0);
        acc[rt][ct] = __builtin_amdgcn_mfma_f32_16x16x32_bf16(Ah[rt], Bh, acc[rt][ct], 0, 0, 0);
      }
    }
  }

  // Epilogue: score = wnorm - 2*dot; per-lane top-2, then 4-stage butterfly.
  u64 b0[2][4], b1[2][4];
  #pragma unroll
  for (int rt = 0; rt < 2; rt++)
    #pragma unroll
    for (int reg = 0; reg < 4; reg++) { b0[rt][reg] = ~0ULL; b1[rt][reg] = ~0ULL; }

  #pragma unroll
  for (int ct = 0; ct < 8; ct++) {
    const int col = kbase + ct * 16 + idx16;
    const float wn = wnorm[col];
    #pragma unroll
    for (int rt = 0; rt < 2; rt++) {
      #pragma unroll
      for (int reg = 0; reg < 4; reg++) {
        const float s = fmaf(-2.0f, acc[rt][ct][reg], wn);
        const u64 p = ((u64)fkey(s) << 32) | (unsigned)col;
        if (p < b1[rt][reg]) {
          if (p < b0[rt][reg]) { b1[rt][reg] = b0[rt][reg]; b0[rt][reg] = p; }
          else                 { b1[rt][reg] = p; }
        }
      }
    }
  }

  #pragma unroll
  for (int m = 1; m <= 8; m <<= 1) {
    #pragma unroll
    for (int rt = 0; rt < 2; rt++) {
      #pragma unroll
      for (int reg = 0; reg < 4; reg++) {
        const u64 o0 = __shfl_xor(b0[rt][reg], m);
        const u64 o1 = __shfl_xor(b1[rt][reg], m);
        if (o0 < b0[rt][reg]) {
          b1[rt][reg] = (b0[rt][reg] < o1) ? b0[rt][reg] : o1;
          b0[rt][reg] = o0;
        } else {
          b1[rt][reg] = (b1[rt][reg] < o0) ? b1[rt][reg] : o0;
        }
      }
    }
  }

  if (idx16 == 0) {
    #pragma unroll
    for (int rt = 0; rt < 2; rt++) {
      #pragma unroll
      for (int reg = 0; reg < 4; reg++) {
        const int row = rowBase + wv * 32 + rt * 16 + quad * 4 + reg;
        pairs[row * 16 + sp * 2 + 0] = b0[rt][reg];
        pairs[row * 16 + sp * 2 + 1] = b1[rt][reg];
      }
    }
  }
}

// ------------------------------------- merge splits + flag + counts ----
__global__ __launch_bounds__(256)
void merge_kernel(const u64* __restrict__ pairs,
                  int* __restrict__ idx, float* __restrict__ counts,
                  int* __restrict__ flags, int* __restrict__ counter) {
  const int row = blockIdx.x * 256 + threadIdx.x;
  const u64* p = &pairs[row * 16];
  u64 B0 = p[0], B1 = p[1];
  #pragma unroll
  for (int s = 1; s < KSPLIT; s++) {
    const u64 c0 = p[s * 2], c1 = p[s * 2 + 1];
    if (c0 < B0) { B1 = (B0 < c1) ? B0 : c1; B0 = c0; }
    else         { B1 = (B1 < c0) ? B1 : c0; }
  }
  const int k = (int)(B0 & 0xffffffffULL);
  idx[row] = k;
  atomicAdd(&counts[k], 1.0f);
  const float s0 = unfkey((unsigned)(B0 >> 32));
  const float s1 = unfkey((unsigned)(B1 >> 32));
  if (s1 - s0 < 2e-4f) {
    const int pos = atomicAdd(counter, 1);
    if (pos < FCAP) flags[pos] = row;
  }
}

// --------------------- np-fp32-emulating recheck; adjusts counts on flips ----
__global__ __launch_bounds__(256)
void recheck_np_kernel(const float* __restrict__ x, const float* __restrict__ w,
                       const float* __restrict__ wnorm,
                       const int* __restrict__ flags, const int* __restrict__ counter,
                       int* __restrict__ idx, float* __restrict__ counts) {
  __shared__ float xs[RPB][DIM];
  __shared__ float x2sh[RPB];
  __shared__ u64 red[RPB][256];

  const int cnt  = min(*counter, FCAP);
  const int base = blockIdx.x * RPB;
  if (base >= cnt) return;
  const int nr = min(RPB, cnt - base);

  #pragma unroll
  for (int r = 0; r < RPB; r++)
    xs[r][threadIdx.x] = (r < nr) ? x[flags[base + r] * DIM + threadIdx.x] : 0.0f;
  __syncthreads();
  if (threadIdx.x < RPB) x2sh[threadIdx.x] = np_sumsq_256(xs[threadIdx.x]);
  __syncthreads();
  double x2d[RPB];
  #pragma unroll
  for (int r = 0; r < RPB; r++) x2d[r] = (double)x2sh[r];

  u64 best[RPB];
  #pragma unroll
  for (int r = 0; r < RPB; r++) best[r] = ~0ULL;

  #pragma unroll 1
  for (int g = 0; g < 4; g++) {
    const int k = threadIdx.x * 4 + g;
    const float* wr = &w[k * DIM];
    const double w2 = (double)wnorm[k];
    double dot[RPB];
    #pragma unroll
    for (int r = 0; r < RPB; r++) dot[r] = 0.0;
    #pragma unroll 1
    for (int d = 0; d < DIM; d += 4) {
      const float4 wv = *(const float4*)&wr[d];
      #pragma unroll
      for (int r = 0; r < RPB; r++) {
        dot[r] = fma((double)xs[r][d],     (double)wv.x, dot[r]);
        dot[r] = fma((double)xs[r][d + 1], (double)wv.y, dot[r]);
        dot[r] = fma((double)xs[r][d + 2], (double)wv.z, dot[r]);
        dot[r] = fma((double)xs[r][d + 3], (double)wv.w, dot[r]);
      }
    }
    #pragma unroll
    for (int r = 0; r < RPB; r++) {
      const float mmf = (float)dot[r];
      const float S1  = (float)(x2d[r] + w2);
      const float D   = (float)((double)S1 - 2.0 * (double)mmf);
      const u64 key = ((u64)fkey(D) << 32) | (unsigned)k;
      if (key < best[r]) best[r] = key;
    }
  }

  #pragma unroll
  for (int r = 0; r < RPB; r++) red[r][threadIdx.x] = best[r];
  __syncthreads();
  #pragma unroll
  for (int off = 128; off > 0; off >>= 1) {
    if ((int)threadIdx.x < off) {
      #pragma unroll
      for (int r = 0; r < RPB; r++) {
        const u64 o = red[r][threadIdx.x + off];
        if (o < red[r][threadIdx.x]) red[r][threadIdx.x] = o;
      }
    }
    __syncthreads();
  }
  if ((int)threadIdx.x < nr) {
    const int row  = flags[base + threadIdx.x];
    const int newk = (int)(red[threadIdx.x][0] & 0xffffffffULL);
    const int oldk = idx[row];
    if (newk != oldk) {
      idx[row] = newk;
      atomicAdd(&counts[newk],  1.0f);
      atomicAdd(&counts[oldk], -1.0f);
    }
  }
}

// ------------------------------- fused prefix scan (starts/cursor) + cs ----
__global__ __launch_bounds__(1024)
void prefix_cs_kernel(const float* __restrict__ ema_cs, const float* __restrict__ counts,
                      int* __restrict__ starts, int* __restrict__ cursor,
                      float* __restrict__ out_cs, float* __restrict__ cs_ws) {
  __shared__ int sc[1024];
  __shared__ float lds[17];
  const int t = threadIdx.x;
  const int ci = (int)counts[t];
  sc[t] = ci;
  const float c = ema_cs[t] * 0.99f + 0.01f * counts[t];
  float v = c;
  #pragma unroll
  for (int off = 32; off > 0; off >>= 1) v += __shfl_down(v, off);
  if ((t & 63) == 0) lds[t >> 6] = v;
  __syncthreads();
  if (t == 0) {
    float n = 0.0f;
    for (int i = 0; i < 16; i++) n += lds[i];
    lds[16] = n;
  }
  __syncthreads();
  const float n = lds[16];
  const float csv = (c + 1e-5f) / (n + 1024.0f * 1e-5f) * n;
  out_cs[t] = csv;
  cs_ws[t]  = csv;
  #pragma unroll
  for (int off = 1; off < 1024; off <<= 1) {
    const int add = (t >= off) ? sc[t - off] : 0;
    __syncthreads();
    sc[t] += add;
    __syncthreads();
  }
  const int excl = sc[t] - ci;
  starts[t] = excl;
  cursor[t] = excl;
}

// ------------------------------------------------------ bucket scatter ----
__global__ __launch_bounds__(256)
void scatter_kernel(const int* __restrict__ idx, int* __restrict__ cursor,
                    int* __restrict__ bucket) {
  const int row = blockIdx.x * 256 + threadIdx.x;
  const int k = idx[row];
  const int pos = atomicAdd(&cursor[k], 1);
  bucket[pos] = row;
}

// ----------------------------------- per-cluster dw reduction (no atomics) ----
__global__ __launch_bounds__(256)
void dw_bucket_kernel(const float4* __restrict__ x4, const int* __restrict__ bucket,
                      const int* __restrict__ starts, const float* __restrict__ counts,
                      float4* __restrict__ dw4) {
  __shared__ float4 red[4][64];
  const int k   = blockIdx.x;
  const int d4  = threadIdx.x & 63;
  const int rg  = threadIdx.x >> 6;
  const int s   = starts[k];
  const int e   = s + (int)counts[k];
  float4 acc = {0.f, 0.f, 0.f, 0.f};
  for (int i = s + rg; i < e; i += 4) {
    const float4 v = x4[bucket[i] * 64 + d4];
    acc.x += v.x; acc.y += v.y; acc.z += v.z; acc.w += v.w;
  }
  red[rg][d4] = acc;
  __syncthreads();
  if (rg == 0) {
    const float4 a1 = red[1][d4], a2 = red[2][d4], a3 = red[3][d4];
    acc.x += a1.x + a2.x + a3.x;
    acc.y += a1.y + a2.y + a3.y;
    acc.z += a1.z + a2.z + a3.z;
    acc.w += a1.w + a2.w + a3.w;
    dw4[k * 64 + d4] = acc;
  }
}

// ------------------------------------------- quantize + loss (no atomics) ----
__global__ __launch_bounds__(256)
void quant_loss_kernel(const float4* __restrict__ x4,
                       const float4* __restrict__ w4,
                       const int* __restrict__ idx,
                       float4* __restrict__ outq,
                       float* __restrict__ partials) {
  __shared__ float lds[4];
  const int g  = blockIdx.x * 256 + threadIdx.x;
  const int n  = g >> 6;
  const int d4 = g & 63;
  const float4 xv = x4[g];
  const int   k  = idx[n];
  const float4 qv = w4[k * 64 + d4];
  float4 r;
  r.x = xv.x + (qv.x - xv.x);
  r.y = xv.y + (qv.y - xv.y);
  r.z = xv.z + (qv.z - xv.z);
  r.w = xv.w + (qv.w - xv.w);
  outq[g] = r;

  const float dx = xv.x - r.x, dy = xv.y - r.y, dz = xv.z - r.z, dwv = xv.w - r.w;
  float s = dx * dx + dy * dy + dz * dz + dwv * dwv;
  #pragma unroll
  for (int off = 32; off > 0; off >>= 1) s += __shfl_down(s, off);
  if ((threadIdx.x & 63) == 0) lds[threadIdx.x >> 6] = s;
  __syncthreads();
  if (threadIdx.x == 0) partials[blockIdx.x] = lds[0] + lds[1] + lds[2] + lds[3];
}

// --------------------------------- fused ema_w/embed (+ loss finalize) ----
__global__ __launch_bounds__(256)
void emb_loss_kernel(const float* __restrict__ ema_w, const float* __restrict__ dw,
                     const float* __restrict__ cs, const float* __restrict__ partials,
                     float* __restrict__ out_ema_w, float* __restrict__ out_embed,
                     float* __restrict__ out_loss) {
  if (blockIdx.x == 1024) {
    __shared__ float lds[4];
    float s = 0.0f;
    for (int i = threadIdx.x; i < 4096; i += 256) s += partials[i];
    #pragma unroll
    for (int off = 32; off > 0; off >>= 1) s += __shfl_down(s, off);
    if ((threadIdx.x & 63) == 0) lds[threadIdx.x >> 6] = s;
    __syncthreads();
    if (threadIdx.x == 0) {
      const float total = lds[0] + lds[1] + lds[2] + lds[3];
      out_loss[0] = 0.25f * (total / 4194304.0f);
    }
    return;
  }
  const int g = blockIdx.x * 256 + threadIdx.x;
  const int k = g >> 8;
  const float e = ema_w[g] * 0.99f + 0.01f * dw[g];
  out_ema_w[g] = e;
  out_embed[g] = e / cs[k];
}

// ------------------------------------------------------------------ launch ----
extern "C" void kernel_launch(void* const* d_in, const int* in_sizes, int n_in,
                              void* d_out, int out_size, void* d_ws, size_t ws_size,
                              hipStream_t stream) {
  const float* x       = (const float*)d_in[0];
  const float* embed_w = (const float*)d_in[1];
  const float* ema_cs  = (const float*)d_in[2];
  const float* ema_w   = (const float*)d_in[3];

  float* out        = (float*)d_out;
  float* out_q      = out;                 // 4194304
  float* out_loss   = out + 4194304;       // 1
  float* out_embed  = out + 4194305;       // 262144
  float* out_cs     = out + 4456449;       // 1024
  float* out_ema_w  = out + 4457473;       // 262144

  char* ws = (char*)d_ws;
  u64*   pairs    = (u64*)  (ws + 0);           // 2 MB [0, 2097152)
  int*   bucket   = (int*)  (ws + 0);           // 64 KB  (alias, post-merge)
  float* dw       = (float*)(ws + 1048576);     // 1 MB   (alias pairs hi, post-merge)
  int*   idx      = (int*)  (ws + 2097152);     // 64 KB  [2097152, 2162688)
  float* counts   = (float*)(ws + 2162688);     // 4 KB
  int*   counter  = (int*)  (ws + 2166784);     // 4 B (adjacent to counts)
  int*   flags    = (int*)  (ws + 2166912);     // 32 KB
  float* wnorm    = (float*)(ws + 2199680);     // 4 KB
  float* cs_ws    = (float*)(ws + 2203776);     // 4 KB
  float* partials = (float*)(ws + 2207872);     // 16 KB
  int*   starts   = (int*)  (ws + 2224256);     // 4 KB
  int*   cursor   = (int*)  (ws + 2228352);     // 4 KB
  ushort* wh      = (ushort*)(ws + 2232448);    // 512 KB [2232448, 2756736)
  ushort* wl      = (ushort*)(ws + 2756736);    // 512 KB [2756736, 3281024)
  // ^ R8/R10 BUG: wl was at 2756608, overlapping wh's last 128 B (code 1023
  //   hi-plane clobbered by code 0 lo-plane) -> deterministic argmin flips.

  // x planes alias out_q (16 MB exactly; overwritten by quant_loss later).
  ushort* xh = (ushort*)out_q;                  // 8 MB
  ushort* xl = (ushort*)out_q + 4194304;        // 8 MB

  hipMemsetAsync(counts, 0, 4100, stream);      // counts + counter

  pack_wnorm_kernel<<<2180, 256, 0, stream>>>(
      (const float4*)x, (const float4*)embed_w, embed_w,
      (uint4*)xh, (uint4*)xl, (uint4*)wh, (uint4*)wl, wnorm);
  dist_mfma_kernel<<<(NROW / MT) * KSPLIT, 256, 0, stream>>>(xh, xl, wh, wl, wnorm, pairs);
  merge_kernel<<<NROW / 256, 256, 0, stream>>>(pairs, idx, counts, flags, counter);
  recheck_np_kernel<<<FCAP / RPB, 256, 0, stream>>>(x, embed_w, wnorm, flags, counter,
                                                    idx, counts);
  prefix_cs_kernel<<<1, 1024, 0, stream>>>(ema_cs, counts, starts, cursor, out_cs, cs_ws);
  scatter_kernel<<<NROW / 256, 256, 0, stream>>>(idx, cursor, bucket);
  dw_bucket_kernel<<<KC, 256, 0, stream>>>((const float4*)x, bucket, starts, counts,
                                           (float4*)dw);
  quant_loss_kernel<<<NROW * 64 / 256, 256, 0, stream>>>(
      (const float4*)x, (const float4*)embed_w, idx, (float4*)out_q, partials);
  emb_loss_kernel<<<KC * DIM / 256 + 1, 256, 0, stream>>>(
      ema_w, dw, cs_ws, partials, out_ema_w, out_embed, out_loss);
}